// Round 1
// baseline (2678.289 us; speedup 1.0000x reference)
//
#include <hip/hip_runtime.h>
#include <cstdint>
#include <cstddef>

#define NEG_SLOPE 0.2f

// ---------- helpers ----------

// monotone map float -> uint so unsigned atomicMax == float max
__device__ __forceinline__ unsigned fmap(float f) {
  unsigned u = __float_as_uint(f);
  return (u & 0x80000000u) ? ~u : (u | 0x80000000u);
}
__device__ __forceinline__ float funmap(unsigned u) {
  return __uint_as_float((u & 0x80000000u) ? (u & 0x7FFFFFFFu) : ~u);
}

// edge e -> (src, dst); self loops appended after the E real edges
__device__ __forceinline__ void edge_sd(const int* __restrict__ ei, int E, int e,
                                        int& s, int& d) {
  if (e < E) { s = ei[e]; d = ei[E + e]; }
  else       { s = e - E; d = s; }
}

// ---------- zero fill ----------
__global__ __launch_bounds__(256) void zero_kernel(float* __restrict__ p, long n) {
  long i = (long)blockIdx.x * blockDim.x + threadIdx.x;
  long stride = (long)gridDim.x * blockDim.x;
  for (; i < n; i += stride) p[i] = 0.f;
}

// ---------- input layernorm over 64 features (wave per row) ----------
__global__ __launch_bounds__(256) void ln64_kernel(
    const float* __restrict__ x, const float* __restrict__ g,
    const float* __restrict__ b, float* __restrict__ y, int n) {
  int row = blockIdx.x * 4 + (threadIdx.x >> 6);
  int l = threadIdx.x & 63;
  if (row >= n) return;
  float v = x[(size_t)row * 64 + l];
  float s = v, sq = v * v;
  #pragma unroll
  for (int o = 32; o; o >>= 1) { s += __shfl_xor(s, o); sq += __shfl_xor(sq, o); }
  float mean = s * (1.f / 64.f);
  float var = sq * (1.f / 64.f) - mean * mean;
  float rstd = rsqrtf(var + 1e-5f);
  y[(size_t)row * 64 + l] = (v - mean) * rstd * g[l] + b[l];
}

// ---------- GEMM: Y[n,FOUT] = X[n,FIN] @ W[FIN,FOUT] (+bias, relu) ----------
// Block: 256 threads = (FOUT/2 col-pairs) x row-groups; 32-row tile in LDS,
// W staged in <=64-row K chunks (LDS <= 48KB).
template <int FIN, int FOUT, bool BR>
__global__ __launch_bounds__(256) void gemm_kernel(
    const float* __restrict__ X, const float* __restrict__ W,
    const float* __restrict__ bias, float* __restrict__ Y, int nrows) {
  constexpr int TILE = 32;
  constexpr int KC = (FIN > 64) ? 64 : FIN;
  constexpr int CP = FOUT / 2;     // col pairs
  constexpr int RGS = 256 / CP;    // row groups
  constexpr int RPT = TILE / RGS;  // rows per thread
  __shared__ float Ws[KC * FOUT];
  __shared__ float Xs[TILE * FIN];
  int tid = threadIdx.x;
  int row0 = blockIdx.x * TILE;

  const float* Xg = X + (size_t)row0 * FIN;
  for (int i = tid * 4; i < TILE * FIN; i += 256 * 4)
    *(float4*)&Xs[i] = *(const float4*)&Xg[i];

  int cp = tid % CP;
  int rg = tid / CP;
  float2 acc[RPT];
  #pragma unroll
  for (int r = 0; r < RPT; r++) acc[r] = make_float2(0.f, 0.f);

  for (int k0 = 0; k0 < FIN; k0 += KC) {
    __syncthreads();  // protect Ws reuse; first iter also covers Xs
    const float* Wg = W + (size_t)k0 * FOUT;
    for (int i = tid * 4; i < KC * FOUT; i += 256 * 4)
      *(float4*)&Ws[i] = *(const float4*)&Wg[i];
    __syncthreads();
    #pragma unroll 4
    for (int k = 0; k < KC; k += 4) {
      float2 w0 = *(const float2*)&Ws[(k + 0) * FOUT + cp * 2];
      float2 w1 = *(const float2*)&Ws[(k + 1) * FOUT + cp * 2];
      float2 w2 = *(const float2*)&Ws[(k + 2) * FOUT + cp * 2];
      float2 w3 = *(const float2*)&Ws[(k + 3) * FOUT + cp * 2];
      #pragma unroll
      for (int r = 0; r < RPT; r++) {
        const float4 xv = *(const float4*)&Xs[(rg * RPT + r) * FIN + k0 + k];
        acc[r].x += xv.x * w0.x + xv.y * w1.x + xv.z * w2.x + xv.w * w3.x;
        acc[r].y += xv.x * w0.y + xv.y * w1.y + xv.z * w2.y + xv.w * w3.y;
      }
    }
  }
  float2 bb = make_float2(0.f, 0.f);
  if constexpr (BR) bb = *(const float2*)&bias[cp * 2];
  #pragma unroll
  for (int r = 0; r < RPT; r++) {
    int row = row0 + rg * RPT + r;
    if (row >= nrows) continue;
    float2 v = acc[r];
    if constexpr (BR) {
      v.x = fmaxf(v.x + bb.x, 0.f);
      v.y = fmaxf(v.y + bb.y, 0.f);
    }
    *(float2*)&Y[(size_t)row * FOUT + cp * 2] = v;
  }
}

// ---------- edge pass A: logits + segment max (thread per edge-head) --------
template <int H, int HD>
__global__ __launch_bounds__(256) void edge_logits_kernel(
    const float* __restrict__ xl, const float* __restrict__ xr,
    const int* __restrict__ ei, int E, int ET, const float* __restrict__ att,
    float* __restrict__ logits, unsigned* __restrict__ M) {
  int t = blockIdx.x * 256 + threadIdx.x;
  int e = t / H;
  int h = t % H;
  if (e >= ET) return;
  int s, d;
  edge_sd(ei, E, e, s, d);
  const float* pl = xl + (size_t)s * (H * HD) + h * HD;
  const float* pr = xr + (size_t)d * (H * HD) + h * HD;
  const float* pa = att + h * HD;
  float acc = 0.f;
  #pragma unroll 8
  for (int c = 0; c < HD; c += 4) {
    float4 a = *(const float4*)(pl + c);
    float4 r = *(const float4*)(pr + c);
    float4 w = *(const float4*)(pa + c);
    float v0 = a.x + r.x; v0 = v0 > 0.f ? v0 : NEG_SLOPE * v0;
    float v1 = a.y + r.y; v1 = v1 > 0.f ? v1 : NEG_SLOPE * v1;
    float v2 = a.z + r.z; v2 = v2 > 0.f ? v2 : NEG_SLOPE * v2;
    float v3 = a.w + r.w; v3 = v3 > 0.f ? v3 : NEG_SLOPE * v3;
    acc += v0 * w.x + v1 * w.y + v2 * w.z + v3 * w.w;
  }
  logits[(size_t)e * H + h] = acc;
  atomicMax(&M[(size_t)d * H + h], fmap(acc));
}

// ---------- edge pass B: p=exp(logit-m); acc[dst]+=p*xl[src]; S[dst]+=p -----
// wave per edge, lane l handles channels l and l+64
template <int H, int HD>
__global__ __launch_bounds__(256) void edge_accum_kernel(
    const float* __restrict__ xl, const int* __restrict__ ei, int E, int ET,
    const float* __restrict__ logits, const unsigned* __restrict__ M,
    float* __restrict__ S, float* __restrict__ acc) {
  int e = blockIdx.x * 4 + (threadIdx.x >> 6);
  int l = threadIdx.x & 63;
  if (e >= ET) return;
  int s, d;
  edge_sd(ei, E, e, s, d);
  int c1 = l, c2 = l + 64;
  int h1 = c1 / HD, h2 = c2 / HD;
  float p1 = __expf(logits[(size_t)e * H + h1] - funmap(M[(size_t)d * H + h1]));
  float p2 = __expf(logits[(size_t)e * H + h2] - funmap(M[(size_t)d * H + h2]));
  atomicAdd(&acc[(size_t)d * 128 + c1], p1 * xl[(size_t)s * 128 + c1]);
  atomicAdd(&acc[(size_t)d * 128 + c2], p2 * xl[(size_t)s * 128 + c2]);
  if (l < H) {
    float ph = __expf(logits[(size_t)e * H + l] - funmap(M[(size_t)d * H + l]));
    atomicAdd(&S[(size_t)d * H + l], ph);
  }
}

// ---------- epilogue: /S, layernorm(128), +0.1*res, relu (wave per row) -----
__global__ __launch_bounds__(256) void epilogue_kernel(
    const float* __restrict__ acc, const float* __restrict__ S,
    const float* __restrict__ res, const float* __restrict__ g,
    const float* __restrict__ b, float* __restrict__ y, int n, int H,
    float resScale, int doRelu) {
  int row = blockIdx.x * 4 + (threadIdx.x >> 6);
  int l = threadIdx.x & 63;
  if (row >= n) return;
  int c1 = l, c2 = l + 64;
  float v1 = acc[(size_t)row * 128 + c1] / S[row * H + ((c1 * H) >> 7)];
  float v2 = acc[(size_t)row * 128 + c2] / S[row * H + ((c2 * H) >> 7)];
  float s = v1 + v2, sq = v1 * v1 + v2 * v2;
  #pragma unroll
  for (int o = 32; o; o >>= 1) { s += __shfl_xor(s, o); sq += __shfl_xor(sq, o); }
  float mean = s * (1.f / 128.f);
  float var = sq * (1.f / 128.f) - mean * mean;
  float rstd = rsqrtf(var + 1e-5f);
  float o1 = (v1 - mean) * rstd * g[c1] + b[c1];
  float o2 = (v2 - mean) * rstd * g[c2] + b[c2];
  if (res) {
    o1 += resScale * res[(size_t)row * 128 + c1];
    o2 += resScale * res[(size_t)row * 128 + c2];
  }
  if (doRelu) { o1 = fmaxf(o1, 0.f); o2 = fmaxf(o2, 0.f); }
  y[(size_t)row * 128 + c1] = o1;
  y[(size_t)row * 128 + c2] = o2;
}

// ---------- final heads: out[n,0]=t_rtt.w2+b2, out[n,1]=t_ret.w2+b2 ---------
__global__ __launch_bounds__(256) void head_out_kernel(
    const float* __restrict__ t_rtt, const float* __restrict__ t_ret,
    const float* __restrict__ w2r, const float* __restrict__ b2r,
    const float* __restrict__ w2e, const float* __restrict__ b2e,
    float* __restrict__ out, int n) {
  int row = blockIdx.x * 4 + (threadIdx.x >> 6);
  int l = threadIdx.x & 63;
  if (row >= n) return;
  float a = t_rtt[(size_t)row * 64 + l] * w2r[l];
  float c = t_ret[(size_t)row * 64 + l] * w2e[l];
  #pragma unroll
  for (int o = 32; o; o >>= 1) { a += __shfl_xor(a, o); c += __shfl_xor(c, o); }
  if (l == 0) {
    out[(size_t)row * 2 + 0] = a + b2r[0];
    out[(size_t)row * 2 + 1] = c + b2e[0];
  }
}

// ---------- launch ----------
extern "C" void kernel_launch(void* const* d_in, const int* in_sizes, int n_in,
                              void* d_out, int out_size, void* d_ws,
                              size_t ws_size, hipStream_t stream) {
  const float* x       = (const float*)d_in[0];
  const int*   ei      = (const int*)d_in[1];
  const float* ln_in_g = (const float*)d_in[2];
  const float* ln_in_b = (const float*)d_in[3];
  const float* w_l1    = (const float*)d_in[4];
  const float* w_r1    = (const float*)d_in[5];
  const float* att1    = (const float*)d_in[6];
  const float* ln1_g   = (const float*)d_in[7];
  const float* ln1_b   = (const float*)d_in[8];
  const float* w_l2    = (const float*)d_in[9];
  const float* w_r2    = (const float*)d_in[10];
  const float* att2    = (const float*)d_in[11];
  const float* ln2_g   = (const float*)d_in[12];
  const float* ln2_b   = (const float*)d_in[13];
  const float* w_l3    = (const float*)d_in[14];
  const float* w_r3    = (const float*)d_in[15];
  const float* att3    = (const float*)d_in[16];
  const float* ln3_g   = (const float*)d_in[17];
  const float* ln3_b   = (const float*)d_in[18];
  const float* rtt_w1  = (const float*)d_in[19];
  const float* rtt_b1  = (const float*)d_in[20];
  const float* rtt_w2  = (const float*)d_in[21];
  const float* rtt_b2  = (const float*)d_in[22];
  const float* ret_w1  = (const float*)d_in[23];
  const float* ret_b1  = (const float*)d_in[24];
  const float* ret_w2  = (const float*)d_in[25];
  const float* ret_b2  = (const float*)d_in[26];

  const int N = in_sizes[0] / 64;
  const int E = in_sizes[1] / 2;
  const int ET = E + N;
  const size_t NF = (size_t)N * 128;

  float* A = (float*)d_ws;          // node features h / residual
  float* B = A + NF;                // xl  (later rtt hidden)
  float* C = B + NF;                // xr  (later ret hidden)
  float* D = C + NF;                // conv accumulator
  unsigned* M = (unsigned*)(D + NF);  // segment max (mapped uint), N*4
  float* S = (float*)(M + (size_t)N * 4);  // segment sum, N*4
  float* P = S + (size_t)N * 4;     // logits, ET*4

  float* out = (float*)d_out;

  const int rowBlocks = (N + 3) / 4;
  const int gemmBlocks = (N + 31) / 32;
  const long zeroCount = (long)NF + (long)N * 8;  // D + M + S
  const int ebH4 = (ET * 4 + 255) / 256;
  const int ebH1 = (ET + 255) / 256;
  const int eaBlocks = (ET + 3) / 4;

  // input layernorm
  ln64_kernel<<<rowBlocks, 256, 0, stream>>>(x, ln_in_g, ln_in_b, A, N);

  // ---- layer 0: 64 -> 128, 4 heads, no residual, relu ----
  gemm_kernel<64, 128, false><<<gemmBlocks, 256, 0, stream>>>(A, w_l1, nullptr, B, N);
  gemm_kernel<64, 128, false><<<gemmBlocks, 256, 0, stream>>>(A, w_r1, nullptr, C, N);
  zero_kernel<<<4096, 256, 0, stream>>>(D, zeroCount);
  edge_logits_kernel<4, 32><<<ebH4, 256, 0, stream>>>(B, C, ei, E, ET, att1, P, M);
  edge_accum_kernel<4, 32><<<eaBlocks, 256, 0, stream>>>(B, ei, E, ET, P, M, S, D);
  epilogue_kernel<<<rowBlocks, 256, 0, stream>>>(D, S, nullptr, ln1_g, ln1_b, A, N, 4, 0.f, 1);

  // ---- layer 1: 128 -> 128, 4 heads, residual 0.1, relu ----
  gemm_kernel<128, 128, false><<<gemmBlocks, 256, 0, stream>>>(A, w_l2, nullptr, B, N);
  gemm_kernel<128, 128, false><<<gemmBlocks, 256, 0, stream>>>(A, w_r2, nullptr, C, N);
  zero_kernel<<<4096, 256, 0, stream>>>(D, zeroCount);
  edge_logits_kernel<4, 32><<<ebH4, 256, 0, stream>>>(B, C, ei, E, ET, att2, P, M);
  edge_accum_kernel<4, 32><<<eaBlocks, 256, 0, stream>>>(B, ei, E, ET, P, M, S, D);
  epilogue_kernel<<<rowBlocks, 256, 0, stream>>>(D, S, A, ln2_g, ln2_b, A, N, 4, 0.1f, 1);

  // ---- layer 2: 128 -> 128, 1 head, residual 0.1, no relu ----
  gemm_kernel<128, 128, false><<<gemmBlocks, 256, 0, stream>>>(A, w_l3, nullptr, B, N);
  gemm_kernel<128, 128, false><<<gemmBlocks, 256, 0, stream>>>(A, w_r3, nullptr, C, N);
  zero_kernel<<<4096, 256, 0, stream>>>(D, zeroCount);
  edge_logits_kernel<1, 128><<<ebH1, 256, 0, stream>>>(B, C, ei, E, ET, att3, P, M);
  edge_accum_kernel<1, 128><<<eaBlocks, 256, 0, stream>>>(B, ei, E, ET, P, M, S, D);
  epilogue_kernel<<<rowBlocks, 256, 0, stream>>>(D, S, A, ln3_g, ln3_b, A, N, 1, 0.1f, 0);

  // ---- prediction heads ----
  gemm_kernel<128, 64, true><<<gemmBlocks, 256, 0, stream>>>(A, rtt_w1, rtt_b1, B, N);
  gemm_kernel<128, 64, true><<<gemmBlocks, 256, 0, stream>>>(A, ret_w1, ret_b1, C, N);
  head_out_kernel<<<rowBlocks, 256, 0, stream>>>(B, C, rtt_w2, rtt_b2, ret_w2,
                                                 ret_b2, out, N);
}

// Round 2
// 1250.895 us; speedup vs baseline: 2.1411x; 2.1411x over previous
//
#include <hip/hip_runtime.h>
#include <cstdint>
#include <cstddef>

#define NEG_SLOPE 0.2f

// ---------- CSR build ----------

__global__ __launch_bounds__(256) void fill_ones_kernel(int* __restrict__ p, int n) {
  int i = blockIdx.x * 256 + threadIdx.x;
  if (i < n) p[i] = 1;  // self-loop contributes degree 1
}

__global__ __launch_bounds__(256) void degree_count_kernel(
    const int* __restrict__ ei, int E, int* __restrict__ deg) {
  int e = blockIdx.x * 256 + threadIdx.x;
  if (e < E) atomicAdd(&deg[ei[E + e]], 1);
}

// inclusive scan per 1024-block
__global__ __launch_bounds__(1024) void scan1_kernel(
    const int* __restrict__ deg, int n, int* __restrict__ incl,
    int* __restrict__ blocksums) {
  __shared__ int sm[1024];
  int t = threadIdx.x;
  int i = blockIdx.x * 1024 + t;
  sm[t] = (i < n) ? deg[i] : 0;
  __syncthreads();
  #pragma unroll
  for (int o = 1; o < 1024; o <<= 1) {
    int a = (t >= o) ? sm[t - o] : 0;
    __syncthreads();
    sm[t] += a;
    __syncthreads();
  }
  if (i < n) incl[i] = sm[t];
  if (t == 1023) blocksums[blockIdx.x] = sm[t];
}

// inclusive scan of block sums (nb <= 1024), single block
__global__ __launch_bounds__(1024) void scan2_kernel(int* __restrict__ bs, int nb) {
  __shared__ int sm[1024];
  int t = threadIdx.x;
  sm[t] = (t < nb) ? bs[t] : 0;
  __syncthreads();
  #pragma unroll
  for (int o = 1; o < 1024; o <<= 1) {
    int a = (t >= o) ? sm[t - o] : 0;
    __syncthreads();
    sm[t] += a;
    __syncthreads();
  }
  if (t < nb) bs[t] = sm[t];
}

// exclusive start -> rowcur (scatter will advance it to row end)
__global__ __launch_bounds__(1024) void scan3_kernel(
    const int* __restrict__ incl, const int* __restrict__ deg,
    const int* __restrict__ bs, int n, int* __restrict__ rowcur) {
  int i = blockIdx.x * 1024 + threadIdx.x;
  if (i >= n) return;
  int off = (blockIdx.x > 0) ? bs[blockIdx.x - 1] : 0;
  rowcur[i] = incl[i] - deg[i] + off;
}

__global__ __launch_bounds__(256) void scatter_kernel(
    const int* __restrict__ ei, int E, int ET, int* __restrict__ rowcur,
    int* __restrict__ csr_src) {
  int e = blockIdx.x * 256 + threadIdx.x;
  if (e >= ET) return;
  int s, d;
  if (e < E) { s = ei[e]; d = ei[E + e]; }
  else       { s = e - E; d = s; }
  int pos = atomicAdd(&rowcur[d], 1);
  csr_src[pos] = s;
}

// ---------- input layernorm over 64 features (wave per row) ----------
__global__ __launch_bounds__(256) void ln64_kernel(
    const float* __restrict__ x, const float* __restrict__ g,
    const float* __restrict__ b, float* __restrict__ y, int n) {
  int row = blockIdx.x * 4 + (threadIdx.x >> 6);
  int l = threadIdx.x & 63;
  if (row >= n) return;
  float v = x[(size_t)row * 64 + l];
  float s = v, sq = v * v;
  #pragma unroll
  for (int o = 32; o; o >>= 1) { s += __shfl_xor(s, o); sq += __shfl_xor(sq, o); }
  float mean = s * (1.f / 64.f);
  float var = sq * (1.f / 64.f) - mean * mean;
  float rstd = rsqrtf(var + 1e-5f);
  y[(size_t)row * 64 + l] = (v - mean) * rstd * g[l] + b[l];
}

// ---------- GEMM: Y[n,FOUT] = X[n,FIN] @ W[FIN,FOUT] (+bias, relu) ----------
template <int FIN, int FOUT, bool BR>
__global__ __launch_bounds__(256) void gemm_kernel(
    const float* __restrict__ X, const float* __restrict__ W,
    const float* __restrict__ bias, float* __restrict__ Y, int nrows) {
  constexpr int TILE = 32;
  constexpr int KC = (FIN > 64) ? 64 : FIN;
  constexpr int CP = FOUT / 2;     // col pairs
  constexpr int RGS = 256 / CP;    // row groups
  constexpr int RPT = TILE / RGS;  // rows per thread
  __shared__ float Ws[KC * FOUT];
  __shared__ float Xs[TILE * FIN];
  int tid = threadIdx.x;
  int row0 = blockIdx.x * TILE;

  const float* Xg = X + (size_t)row0 * FIN;
  for (int i = tid * 4; i < TILE * FIN; i += 256 * 4)
    *(float4*)&Xs[i] = *(const float4*)&Xg[i];

  int cp = tid % CP;
  int rg = tid / CP;
  float2 acc[RPT];
  #pragma unroll
  for (int r = 0; r < RPT; r++) acc[r] = make_float2(0.f, 0.f);

  for (int k0 = 0; k0 < FIN; k0 += KC) {
    __syncthreads();
    const float* Wg = W + (size_t)k0 * FOUT;
    for (int i = tid * 4; i < KC * FOUT; i += 256 * 4)
      *(float4*)&Ws[i] = *(const float4*)&Wg[i];
    __syncthreads();
    #pragma unroll 4
    for (int k = 0; k < KC; k += 4) {
      float2 w0 = *(const float2*)&Ws[(k + 0) * FOUT + cp * 2];
      float2 w1 = *(const float2*)&Ws[(k + 1) * FOUT + cp * 2];
      float2 w2 = *(const float2*)&Ws[(k + 2) * FOUT + cp * 2];
      float2 w3 = *(const float2*)&Ws[(k + 3) * FOUT + cp * 2];
      #pragma unroll
      for (int r = 0; r < RPT; r++) {
        const float4 xv = *(const float4*)&Xs[(rg * RPT + r) * FIN + k0 + k];
        acc[r].x += xv.x * w0.x + xv.y * w1.x + xv.z * w2.x + xv.w * w3.x;
        acc[r].y += xv.x * w0.y + xv.y * w1.y + xv.z * w2.y + xv.w * w3.y;
      }
    }
  }
  float2 bb = make_float2(0.f, 0.f);
  if constexpr (BR) bb = *(const float2*)&bias[cp * 2];
  #pragma unroll
  for (int r = 0; r < RPT; r++) {
    int row = row0 + rg * RPT + r;
    if (row >= nrows) continue;
    float2 v = acc[r];
    if constexpr (BR) {
      v.x = fmaxf(v.x + bb.x, 0.f);
      v.y = fmaxf(v.y + bb.y, 0.f);
    }
    *(float2*)&Y[(size_t)row * FOUT + cp * 2] = v;
  }
}

// ---------- fused GAT layer: online-softmax aggregation + LN + res + relu ---
// Wave per dst row. Lane l owns channels 2l, 2l+1 (same head, H in {1,4}).
// row_end = CSR cursor after scatter (== exclusive end); start = end - deg.
template <int H>
__global__ __launch_bounds__(256) void gat_fused_kernel(
    const float* __restrict__ xl, const float* __restrict__ xr,
    const int* __restrict__ csr_src, const int* __restrict__ row_end,
    const int* __restrict__ deg, const float* __restrict__ att,
    const float* __restrict__ res, const float* __restrict__ g,
    const float* __restrict__ b, float* __restrict__ y, int n,
    float resScale, int doRelu) {
  int row = blockIdx.x * 4 + (threadIdx.x >> 6);
  int l = threadIdx.x & 63;
  if (row >= n) return;
  int end = row_end[row];
  int start = end - deg[row];

  float2 xrv = *(const float2*)&xr[(size_t)row * 128 + 2 * l];
  float2 av  = *(const float2*)&att[2 * l];

  float m = -1e30f, s = 0.f;
  float2 acc = make_float2(0.f, 0.f);

  // software-pipelined gather
  int idx = start;
  int src0 = csr_src[idx];
  float2 xlv_n = *(const float2*)&xl[(size_t)src0 * 128 + 2 * l];

  while (idx < end) {
    float2 xlv = xlv_n;
    idx++;
    if (idx < end) {
      int sn = csr_src[idx];
      xlv_n = *(const float2*)&xl[(size_t)sn * 128 + 2 * l];
    }
    float v0 = xlv.x + xrv.x; v0 = v0 > 0.f ? v0 : NEG_SLOPE * v0;
    float v1 = xlv.y + xrv.y; v1 = v1 > 0.f ? v1 : NEG_SLOPE * v1;
    float p = v0 * av.x + v1 * av.y;
    if constexpr (H == 1) {          // logit over all 128 channels
      #pragma unroll
      for (int o = 32; o; o >>= 1) p += __shfl_xor(p, o);
    } else {                         // H=4: head group = 16 lanes
      #pragma unroll
      for (int o = 8; o; o >>= 1) p += __shfl_xor(p, o);
    }
    float nm = fmaxf(m, p);
    float al = __expf(m - nm);
    float e  = __expf(p - nm);
    s = s * al + e;
    acc.x = acc.x * al + e * xlv.x;
    acc.y = acc.y * al + e * xlv.y;
    m = nm;
  }

  float inv = 1.f / s;
  float o0 = acc.x * inv, o1 = acc.y * inv;

  // fused LayerNorm(128) + residual + relu
  float sum = o0 + o1, sq = o0 * o0 + o1 * o1;
  #pragma unroll
  for (int o = 32; o; o >>= 1) { sum += __shfl_xor(sum, o); sq += __shfl_xor(sq, o); }
  float mean = sum * (1.f / 128.f);
  float var = sq * (1.f / 128.f) - mean * mean;
  float rstd = rsqrtf(var + 1e-5f);
  float2 gv = *(const float2*)&g[2 * l];
  float2 bv = *(const float2*)&b[2 * l];
  float r0 = (o0 - mean) * rstd * gv.x + bv.x;
  float r1 = (o1 - mean) * rstd * gv.y + bv.y;
  if (res) {
    float2 rv = *(const float2*)&res[(size_t)row * 128 + 2 * l];
    r0 += resScale * rv.x;
    r1 += resScale * rv.y;
  }
  if (doRelu) { r0 = fmaxf(r0, 0.f); r1 = fmaxf(r1, 0.f); }
  *(float2*)&y[(size_t)row * 128 + 2 * l] = make_float2(r0, r1);
}

// ---------- final heads ----------
__global__ __launch_bounds__(256) void head_out_kernel(
    const float* __restrict__ t_rtt, const float* __restrict__ t_ret,
    const float* __restrict__ w2r, const float* __restrict__ b2r,
    const float* __restrict__ w2e, const float* __restrict__ b2e,
    float* __restrict__ out, int n) {
  int row = blockIdx.x * 4 + (threadIdx.x >> 6);
  int l = threadIdx.x & 63;
  if (row >= n) return;
  float a = t_rtt[(size_t)row * 64 + l] * w2r[l];
  float c = t_ret[(size_t)row * 64 + l] * w2e[l];
  #pragma unroll
  for (int o = 32; o; o >>= 1) { a += __shfl_xor(a, o); c += __shfl_xor(c, o); }
  if (l == 0) {
    out[(size_t)row * 2 + 0] = a + b2r[0];
    out[(size_t)row * 2 + 1] = c + b2e[0];
  }
}

// ---------- launch ----------
extern "C" void kernel_launch(void* const* d_in, const int* in_sizes, int n_in,
                              void* d_out, int out_size, void* d_ws,
                              size_t ws_size, hipStream_t stream) {
  const float* x       = (const float*)d_in[0];
  const int*   ei      = (const int*)d_in[1];
  const float* ln_in_g = (const float*)d_in[2];
  const float* ln_in_b = (const float*)d_in[3];
  const float* w_l1    = (const float*)d_in[4];
  const float* w_r1    = (const float*)d_in[5];
  const float* att1    = (const float*)d_in[6];
  const float* ln1_g   = (const float*)d_in[7];
  const float* ln1_b   = (const float*)d_in[8];
  const float* w_l2    = (const float*)d_in[9];
  const float* w_r2    = (const float*)d_in[10];
  const float* att2    = (const float*)d_in[11];
  const float* ln2_g   = (const float*)d_in[12];
  const float* ln2_b   = (const float*)d_in[13];
  const float* w_l3    = (const float*)d_in[14];
  const float* w_r3    = (const float*)d_in[15];
  const float* att3    = (const float*)d_in[16];
  const float* ln3_g   = (const float*)d_in[17];
  const float* ln3_b   = (const float*)d_in[18];
  const float* rtt_w1  = (const float*)d_in[19];
  const float* rtt_b1  = (const float*)d_in[20];
  const float* rtt_w2  = (const float*)d_in[21];
  const float* rtt_b2  = (const float*)d_in[22];
  const float* ret_w1  = (const float*)d_in[23];
  const float* ret_b1  = (const float*)d_in[24];
  const float* ret_w2  = (const float*)d_in[25];
  const float* ret_b2  = (const float*)d_in[26];

  const int N = in_sizes[0] / 64;
  const int E = in_sizes[1] / 2;
  const int ET = E + N;
  const size_t NF = (size_t)N * 128;

  float* A = (float*)d_ws;            // node features h / residual
  float* B = A + NF;                  // xl (later rtt hidden)
  float* C = B + NF;                  // xr (later ret hidden)
  int* deg     = (int*)(C + NF);      // N
  int* rowcur  = deg + N;             // N (becomes row_end after scatter)
  int* incl    = rowcur + N;          // N
  int* bsums   = incl + N;            // 1024
  int* csr_src = bsums + 1024;        // ET

  float* out = (float*)d_out;

  const int rowBlocks  = (N + 3) / 4;
  const int gemmBlocks = (N + 31) / 32;
  const int NB = (N + 1023) / 1024;   // scan blocks (98 <= 1024)

  // ---- CSR build (by dst) ----
  fill_ones_kernel<<<(N + 255) / 256, 256, 0, stream>>>(deg, N);
  degree_count_kernel<<<(E + 255) / 256, 256, 0, stream>>>(ei, E, deg);
  scan1_kernel<<<NB, 1024, 0, stream>>>(deg, N, incl, bsums);
  scan2_kernel<<<1, 1024, 0, stream>>>(bsums, NB);
  scan3_kernel<<<NB, 1024, 0, stream>>>(incl, deg, bsums, N, rowcur);
  scatter_kernel<<<(ET + 255) / 256, 256, 0, stream>>>(ei, E, ET, rowcur, csr_src);

  // ---- input layernorm ----
  ln64_kernel<<<rowBlocks, 256, 0, stream>>>(x, ln_in_g, ln_in_b, A, N);

  // ---- layer 0: 64 -> 128, 4 heads, no residual, relu ----
  gemm_kernel<64, 128, false><<<gemmBlocks, 256, 0, stream>>>(A, w_l1, nullptr, B, N);
  gemm_kernel<64, 128, false><<<gemmBlocks, 256, 0, stream>>>(A, w_r1, nullptr, C, N);
  gat_fused_kernel<4><<<rowBlocks, 256, 0, stream>>>(
      B, C, csr_src, rowcur, deg, att1, nullptr, ln1_g, ln1_b, A, N, 0.f, 1);

  // ---- layer 1: 128 -> 128, 4 heads, residual 0.1, relu ----
  gemm_kernel<128, 128, false><<<gemmBlocks, 256, 0, stream>>>(A, w_l2, nullptr, B, N);
  gemm_kernel<128, 128, false><<<gemmBlocks, 256, 0, stream>>>(A, w_r2, nullptr, C, N);
  gat_fused_kernel<4><<<rowBlocks, 256, 0, stream>>>(
      B, C, csr_src, rowcur, deg, att2, A, ln2_g, ln2_b, A, N, 0.1f, 1);

  // ---- layer 2: 128 -> 128, 1 head, residual 0.1, no relu ----
  gemm_kernel<128, 128, false><<<gemmBlocks, 256, 0, stream>>>(A, w_l3, nullptr, B, N);
  gemm_kernel<128, 128, false><<<gemmBlocks, 256, 0, stream>>>(A, w_r3, nullptr, C, N);
  gat_fused_kernel<1><<<rowBlocks, 256, 0, stream>>>(
      B, C, csr_src, rowcur, deg, att3, A, ln3_g, ln3_b, A, N, 0.1f, 0);

  // ---- prediction heads ----
  gemm_kernel<128, 64, true><<<gemmBlocks, 256, 0, stream>>>(A, rtt_w1, rtt_b1, B, N);
  gemm_kernel<128, 64, true><<<gemmBlocks, 256, 0, stream>>>(A, ret_w1, ret_b1, C, N);
  head_out_kernel<<<rowBlocks, 256, 0, stream>>>(B, C, rtt_w2, rtt_b2, ret_w2,
                                                 ret_b2, out, N);
}

// Round 3
// 880.844 us; speedup vs baseline: 3.0406x; 1.4201x over previous
//
#include <hip/hip_runtime.h>
#include <cstdint>
#include <cstddef>

#define NEG_SLOPE 0.2f

// ---------- CSR build ----------

__global__ __launch_bounds__(256) void fill_ones_kernel(int* __restrict__ p, int n) {
  int i = blockIdx.x * 256 + threadIdx.x;
  if (i < n) p[i] = 1;  // self-loop contributes degree 1
}

__global__ __launch_bounds__(256) void degree_count_kernel(
    const int* __restrict__ ei, int E, int* __restrict__ deg) {
  int e = blockIdx.x * 256 + threadIdx.x;
  if (e < E) atomicAdd(&deg[ei[E + e]], 1);
}

// inclusive scan per 1024-block
__global__ __launch_bounds__(1024) void scan1_kernel(
    const int* __restrict__ deg, int n, int* __restrict__ incl,
    int* __restrict__ blocksums) {
  __shared__ int sm[1024];
  int t = threadIdx.x;
  int i = blockIdx.x * 1024 + t;
  sm[t] = (i < n) ? deg[i] : 0;
  __syncthreads();
  #pragma unroll
  for (int o = 1; o < 1024; o <<= 1) {
    int a = (t >= o) ? sm[t - o] : 0;
    __syncthreads();
    sm[t] += a;
    __syncthreads();
  }
  if (i < n) incl[i] = sm[t];
  if (t == 1023) blocksums[blockIdx.x] = sm[t];
}

__global__ __launch_bounds__(1024) void scan2_kernel(int* __restrict__ bs, int nb) {
  __shared__ int sm[1024];
  int t = threadIdx.x;
  sm[t] = (t < nb) ? bs[t] : 0;
  __syncthreads();
  #pragma unroll
  for (int o = 1; o < 1024; o <<= 1) {
    int a = (t >= o) ? sm[t - o] : 0;
    __syncthreads();
    sm[t] += a;
    __syncthreads();
  }
  if (t < nb) bs[t] = sm[t];
}

__global__ __launch_bounds__(1024) void scan3_kernel(
    const int* __restrict__ incl, const int* __restrict__ deg,
    const int* __restrict__ bs, int n, int* __restrict__ rowcur) {
  int i = blockIdx.x * 1024 + threadIdx.x;
  if (i >= n) return;
  int off = (blockIdx.x > 0) ? bs[blockIdx.x - 1] : 0;
  rowcur[i] = incl[i] - deg[i] + off;
}

__global__ __launch_bounds__(256) void scatter_kernel(
    const int* __restrict__ ei, int E, int ET, int* __restrict__ rowcur,
    int* __restrict__ csr_src) {
  int e = blockIdx.x * 256 + threadIdx.x;
  if (e >= ET) return;
  int s, d;
  if (e < E) { s = ei[e]; d = ei[E + e]; }
  else       { s = e - E; d = s; }
  int pos = atomicAdd(&rowcur[d], 1);
  csr_src[pos] = s;
}

// ---------- input layernorm over 64 features (wave per row) ----------
__global__ __launch_bounds__(256) void ln64_kernel(
    const float* __restrict__ x, const float* __restrict__ g,
    const float* __restrict__ b, float* __restrict__ y, int n) {
  int row = blockIdx.x * 4 + (threadIdx.x >> 6);
  int l = threadIdx.x & 63;
  if (row >= n) return;
  float v = x[(size_t)row * 64 + l];
  float s = v, sq = v * v;
  #pragma unroll
  for (int o = 32; o; o >>= 1) { s += __shfl_xor(s, o); sq += __shfl_xor(sq, o); }
  float mean = s * (1.f / 64.f);
  float var = sq * (1.f / 64.f) - mean * mean;
  float rstd = rsqrtf(var + 1e-5f);
  y[(size_t)row * 64 + l] = (v - mean) * rstd * g[l] + b[l];
}

// ---------- GEMM: Y[n,FOUT] = X[n,FIN] @ W[FIN,FOUT] (+bias, relu) ----------
// 128-row tile, 256 threads, 8 rows x 8 cols per thread (FOUT=128)
// or 4 rows x 8 cols (FOUT=64). X transposed in LDS [k][row] (pitch 132),
// W bank-rotation swizzled: swz(c) = c + ((c>>5)<<2) -> 2-way (free) reads.
template <int FIN, int FOUT, bool BR>
__global__ __launch_bounds__(256, 2) void gemm_kernel(
    const float* __restrict__ X, const float* __restrict__ W,
    const float* __restrict__ bias, float* __restrict__ Y, int nrows) {
  constexpr int TR = 128;
  constexpr int KC = (FIN < 64) ? FIN : 64;
  constexpr int CG = FOUT / 8;   // col groups: 16 or 8
  constexpr int RG = 256 / CG;   // row groups: 16 or 32
  constexpr int RPT = TR / RG;   // rows/thread: 8 or 4
  constexpr int XP = TR + 4;     // 132
  constexpr int WP = FOUT + ((FOUT >> 5) << 2) + 4;  // swizzled pitch
  __shared__ float Xs[KC * XP];
  __shared__ float Ws[KC * WP];

  const int tid = threadIdx.x;
  const int row0 = blockIdx.x * TR;
  const int c0 = (tid % CG) * 8;
  const int r0 = (tid / CG) * RPT;
  const int wofs = c0 + ((c0 >> 5) << 2);  // swizzled col offset

  float acc[RPT][8];
  #pragma unroll
  for (int r = 0; r < RPT; r++)
    #pragma unroll
    for (int q = 0; q < 8; q++) acc[r][q] = 0.f;

  for (int k0 = 0; k0 < FIN; k0 += KC) {
    __syncthreads();
    // stage X transposed
    constexpr int NX = TR * KC / 4;
    for (int i = tid; i < NX; i += 256) {
      int r = i / (KC / 4);
      int kq = (i % (KC / 4)) * 4;
      float4 v = make_float4(0.f, 0.f, 0.f, 0.f);
      if (row0 + r < nrows)
        v = *(const float4*)&X[(size_t)(row0 + r) * FIN + k0 + kq];
      Xs[(kq + 0) * XP + r] = v.x;
      Xs[(kq + 1) * XP + r] = v.y;
      Xs[(kq + 2) * XP + r] = v.z;
      Xs[(kq + 3) * XP + r] = v.w;
    }
    // stage W swizzled
    constexpr int NW = KC * FOUT / 4;
    for (int i = tid; i < NW; i += 256) {
      int k = i / (FOUT / 4);
      int c = (i % (FOUT / 4)) * 4;
      float4 v = *(const float4*)&W[(size_t)(k0 + k) * FOUT + c];
      *(float4*)&Ws[k * WP + c + ((c >> 5) << 2)] = v;
    }
    __syncthreads();
    #pragma unroll 4
    for (int k = 0; k < KC; k++) {
      const float4 wa = *(const float4*)&Ws[k * WP + wofs];
      const float4 wb = *(const float4*)&Ws[k * WP + wofs + 4];
      float xv[RPT];
      #pragma unroll
      for (int rr = 0; rr < RPT; rr += 4) {
        float4 xq = *(const float4*)&Xs[k * XP + r0 + rr];
        xv[rr] = xq.x; xv[rr + 1] = xq.y; xv[rr + 2] = xq.z; xv[rr + 3] = xq.w;
      }
      #pragma unroll
      for (int r = 0; r < RPT; r++) {
        acc[r][0] += xv[r] * wa.x;
        acc[r][1] += xv[r] * wa.y;
        acc[r][2] += xv[r] * wa.z;
        acc[r][3] += xv[r] * wa.w;
        acc[r][4] += xv[r] * wb.x;
        acc[r][5] += xv[r] * wb.y;
        acc[r][6] += xv[r] * wb.z;
        acc[r][7] += xv[r] * wb.w;
      }
    }
  }
  float4 ba = make_float4(0.f, 0.f, 0.f, 0.f), bb = ba;
  if constexpr (BR) {
    ba = *(const float4*)&bias[c0];
    bb = *(const float4*)&bias[c0 + 4];
  }
  #pragma unroll
  for (int r = 0; r < RPT; r++) {
    int row = row0 + r0 + r;
    if (row >= nrows) continue;
    float4 va = make_float4(acc[r][0], acc[r][1], acc[r][2], acc[r][3]);
    float4 vb = make_float4(acc[r][4], acc[r][5], acc[r][6], acc[r][7]);
    if constexpr (BR) {
      va.x = fmaxf(va.x + ba.x, 0.f); va.y = fmaxf(va.y + ba.y, 0.f);
      va.z = fmaxf(va.z + ba.z, 0.f); va.w = fmaxf(va.w + ba.w, 0.f);
      vb.x = fmaxf(vb.x + bb.x, 0.f); vb.y = fmaxf(vb.y + bb.y, 0.f);
      vb.z = fmaxf(vb.z + bb.z, 0.f); vb.w = fmaxf(vb.w + bb.w, 0.f);
    }
    *(float4*)&Y[(size_t)row * FOUT + c0] = va;
    *(float4*)&Y[(size_t)row * FOUT + c0 + 4] = vb;
  }
}

// ---------- fused GAT layer -------------------------------------------------
// Wave per dst row; each 32-lane HALF processes its own edge stream
// (half 0: even CSR slots, half 1: odd). Lane ll owns channels 4ll..4ll+3.
// No max-subtraction (logits bounded ~|5| here, exp safe in fp32) -> plain
// sums; halves combine with one xor-32 add. Fused LN + residual + relu.
template <int H>
__global__ __launch_bounds__(256) void gat_fused_kernel(
    const float* __restrict__ xl, const float* __restrict__ xr,
    const int* __restrict__ csr_src, const int* __restrict__ row_end,
    const int* __restrict__ deg, const float* __restrict__ att,
    const float* __restrict__ res, const float* __restrict__ g,
    const float* __restrict__ b, float* __restrict__ y, int n,
    float resScale, int doRelu) {
  int row = blockIdx.x * 4 + (threadIdx.x >> 6);
  if (row >= n) return;
  int l = threadIdx.x & 63;
  int half = l >> 5;
  int ll = l & 31;
  int c = ll * 4;
  int end = row_end[row];
  int dg = deg[row];
  int start = end - dg;
  int cnt = (dg + 1 - half) >> 1;

  const float4 xrv = *(const float4*)&xr[(size_t)row * 128 + c];
  const float4 av  = *(const float4*)&att[c];

  float s = 0.f;
  float a0 = 0.f, a1 = 0.f, a2 = 0.f, a3 = 0.f;

  int idx = start + half;
  float4 xn = make_float4(0.f, 0.f, 0.f, 0.f);
  if (cnt > 0) {
    int s0 = csr_src[idx];
    xn = *(const float4*)&xl[(size_t)s0 * 128 + c];
  }
  for (int i = 0; i < cnt; i++) {
    float4 xv = xn;
    if (i + 1 < cnt) {
      int sn = csr_src[idx + 2];
      xn = *(const float4*)&xl[(size_t)sn * 128 + c];
    }
    idx += 2;
    float v0 = xv.x + xrv.x; v0 = v0 > 0.f ? v0 : NEG_SLOPE * v0;
    float v1 = xv.y + xrv.y; v1 = v1 > 0.f ? v1 : NEG_SLOPE * v1;
    float v2 = xv.z + xrv.z; v2 = v2 > 0.f ? v2 : NEG_SLOPE * v2;
    float v3 = xv.w + xrv.w; v3 = v3 > 0.f ? v3 : NEG_SLOPE * v3;
    float p = v0 * av.x + v1 * av.y + v2 * av.z + v3 * av.w;
    if constexpr (H == 1) {
      #pragma unroll
      for (int o = 16; o; o >>= 1) p += __shfl_xor(p, o);
    } else {  // H=4: head group = 8 lanes (32 channels)
      #pragma unroll
      for (int o = 4; o; o >>= 1) p += __shfl_xor(p, o);
    }
    float e = __expf(p);
    s += e;
    a0 += e * xv.x; a1 += e * xv.y; a2 += e * xv.z; a3 += e * xv.w;
  }
  // combine the two half-wave streams (plain sums)
  s  += __shfl_xor(s, 32);
  a0 += __shfl_xor(a0, 32);
  a1 += __shfl_xor(a1, 32);
  a2 += __shfl_xor(a2, 32);
  a3 += __shfl_xor(a3, 32);

  float inv = 1.f / s;
  float o0 = a0 * inv, o1 = a1 * inv, o2 = a2 * inv, o3 = a3 * inv;

  // LayerNorm over 128 (reduce within the 32-lane half; both halves identical)
  float sum = o0 + o1 + o2 + o3;
  float sq = o0 * o0 + o1 * o1 + o2 * o2 + o3 * o3;
  #pragma unroll
  for (int o = 16; o; o >>= 1) { sum += __shfl_xor(sum, o); sq += __shfl_xor(sq, o); }
  float mean = sum * (1.f / 128.f);
  float var = sq * (1.f / 128.f) - mean * mean;
  float rstd = rsqrtf(var + 1e-5f);
  const float4 gv = *(const float4*)&g[c];
  const float4 bv = *(const float4*)&b[c];
  float r0 = (o0 - mean) * rstd * gv.x + bv.x;
  float r1 = (o1 - mean) * rstd * gv.y + bv.y;
  float r2 = (o2 - mean) * rstd * gv.z + bv.z;
  float r3 = (o3 - mean) * rstd * gv.w + bv.w;
  if (res) {
    const float4 rv = *(const float4*)&res[(size_t)row * 128 + c];
    r0 += resScale * rv.x; r1 += resScale * rv.y;
    r2 += resScale * rv.z; r3 += resScale * rv.w;
  }
  if (doRelu) {
    r0 = fmaxf(r0, 0.f); r1 = fmaxf(r1, 0.f);
    r2 = fmaxf(r2, 0.f); r3 = fmaxf(r3, 0.f);
  }
  if (half == 0)
    *(float4*)&y[(size_t)row * 128 + c] = make_float4(r0, r1, r2, r3);
}

// ---------- final heads ----------
__global__ __launch_bounds__(256) void head_out_kernel(
    const float* __restrict__ t_rtt, const float* __restrict__ t_ret,
    const float* __restrict__ w2r, const float* __restrict__ b2r,
    const float* __restrict__ w2e, const float* __restrict__ b2e,
    float* __restrict__ out, int n) {
  int row = blockIdx.x * 4 + (threadIdx.x >> 6);
  int l = threadIdx.x & 63;
  if (row >= n) return;
  float a = t_rtt[(size_t)row * 64 + l] * w2r[l];
  float c = t_ret[(size_t)row * 64 + l] * w2e[l];
  #pragma unroll
  for (int o = 32; o; o >>= 1) { a += __shfl_xor(a, o); c += __shfl_xor(c, o); }
  if (l == 0) {
    out[(size_t)row * 2 + 0] = a + b2r[0];
    out[(size_t)row * 2 + 1] = c + b2e[0];
  }
}

// ---------- launch ----------
extern "C" void kernel_launch(void* const* d_in, const int* in_sizes, int n_in,
                              void* d_out, int out_size, void* d_ws,
                              size_t ws_size, hipStream_t stream) {
  const float* x       = (const float*)d_in[0];
  const int*   ei      = (const int*)d_in[1];
  const float* ln_in_g = (const float*)d_in[2];
  const float* ln_in_b = (const float*)d_in[3];
  const float* w_l1    = (const float*)d_in[4];
  const float* w_r1    = (const float*)d_in[5];
  const float* att1    = (const float*)d_in[6];
  const float* ln1_g   = (const float*)d_in[7];
  const float* ln1_b   = (const float*)d_in[8];
  const float* w_l2    = (const float*)d_in[9];
  const float* w_r2    = (const float*)d_in[10];
  const float* att2    = (const float*)d_in[11];
  const float* ln2_g   = (const float*)d_in[12];
  const float* ln2_b   = (const float*)d_in[13];
  const float* w_l3    = (const float*)d_in[14];
  const float* w_r3    = (const float*)d_in[15];
  const float* att3    = (const float*)d_in[16];
  const float* ln3_g   = (const float*)d_in[17];
  const float* ln3_b   = (const float*)d_in[18];
  const float* rtt_w1  = (const float*)d_in[19];
  const float* rtt_b1  = (const float*)d_in[20];
  const float* rtt_w2  = (const float*)d_in[21];
  const float* rtt_b2  = (const float*)d_in[22];
  const float* ret_w1  = (const float*)d_in[23];
  const float* ret_b1  = (const float*)d_in[24];
  const float* ret_w2  = (const float*)d_in[25];
  const float* ret_b2  = (const float*)d_in[26];

  const int N = in_sizes[0] / 64;
  const int E = in_sizes[1] / 2;
  const int ET = E + N;
  const size_t NF = (size_t)N * 128;

  float* A = (float*)d_ws;            // node features h / residual
  float* B = A + NF;                  // xl (later rtt hidden)
  float* C = B + NF;                  // xr (later ret hidden)
  int* deg     = (int*)(C + NF);      // N
  int* rowcur  = deg + N;             // N (becomes row_end after scatter)
  int* incl    = rowcur + N;          // N
  int* bsums   = incl + N;            // 1024
  int* csr_src = bsums + 1024;        // ET

  float* out = (float*)d_out;

  const int rowBlocks  = (N + 3) / 4;
  const int gemmBlocks = (N + 127) / 128;
  const int NB = (N + 1023) / 1024;

  // ---- CSR build (by dst) ----
  fill_ones_kernel<<<(N + 255) / 256, 256, 0, stream>>>(deg, N);
  degree_count_kernel<<<(E + 255) / 256, 256, 0, stream>>>(ei, E, deg);
  scan1_kernel<<<NB, 1024, 0, stream>>>(deg, N, incl, bsums);
  scan2_kernel<<<1, 1024, 0, stream>>>(bsums, NB);
  scan3_kernel<<<NB, 1024, 0, stream>>>(incl, deg, bsums, N, rowcur);
  scatter_kernel<<<(ET + 255) / 256, 256, 0, stream>>>(ei, E, ET, rowcur, csr_src);

  // ---- input layernorm ----
  ln64_kernel<<<rowBlocks, 256, 0, stream>>>(x, ln_in_g, ln_in_b, A, N);

  // ---- layer 0: 64 -> 128, 4 heads, no residual, relu ----
  gemm_kernel<64, 128, false><<<gemmBlocks, 256, 0, stream>>>(A, w_l1, nullptr, B, N);
  gemm_kernel<64, 128, false><<<gemmBlocks, 256, 0, stream>>>(A, w_r1, nullptr, C, N);
  gat_fused_kernel<4><<<rowBlocks, 256, 0, stream>>>(
      B, C, csr_src, rowcur, deg, att1, nullptr, ln1_g, ln1_b, A, N, 0.f, 1);

  // ---- layer 1: 128 -> 128, 4 heads, residual 0.1, relu ----
  gemm_kernel<128, 128, false><<<gemmBlocks, 256, 0, stream>>>(A, w_l2, nullptr, B, N);
  gemm_kernel<128, 128, false><<<gemmBlocks, 256, 0, stream>>>(A, w_r2, nullptr, C, N);
  gat_fused_kernel<4><<<rowBlocks, 256, 0, stream>>>(
      B, C, csr_src, rowcur, deg, att2, A, ln2_g, ln2_b, A, N, 0.1f, 1);

  // ---- layer 2: 128 -> 128, 1 head, residual 0.1, no relu ----
  gemm_kernel<128, 128, false><<<gemmBlocks, 256, 0, stream>>>(A, w_l3, nullptr, B, N);
  gemm_kernel<128, 128, false><<<gemmBlocks, 256, 0, stream>>>(A, w_r3, nullptr, C, N);
  gat_fused_kernel<1><<<rowBlocks, 256, 0, stream>>>(
      B, C, csr_src, rowcur, deg, att3, A, ln3_g, ln3_b, A, N, 0.1f, 0);

  // ---- prediction heads ----
  gemm_kernel<128, 64, true><<<gemmBlocks, 256, 0, stream>>>(A, rtt_w1, rtt_b1, B, N);
  gemm_kernel<128, 64, true><<<gemmBlocks, 256, 0, stream>>>(A, ret_w1, ret_b1, C, N);
  head_out_kernel<<<rowBlocks, 256, 0, stream>>>(B, C, rtt_w2, rtt_b2, ret_w2,
                                                 ret_b2, out, N);
}

// Round 4
// 849.365 us; speedup vs baseline: 3.1533x; 1.0371x over previous
//
#include <hip/hip_runtime.h>
#include <cstdint>
#include <cstddef>

#define NEG_SLOPE 0.2f

typedef float f4v __attribute__((ext_vector_type(4)));

// ---------- CSR build ----------

__global__ __launch_bounds__(256) void fill_ones_kernel(int* __restrict__ p, int n) {
  int i = blockIdx.x * 256 + threadIdx.x;
  if (i < n) p[i] = 1;  // self-loop contributes degree 1
}

__global__ __launch_bounds__(256) void degree_count_kernel(
    const int* __restrict__ ei, int E, int* __restrict__ deg) {
  int e = blockIdx.x * 256 + threadIdx.x;
  if (e < E) atomicAdd(&deg[ei[E + e]], 1);
}

__global__ __launch_bounds__(1024) void scan1_kernel(
    const int* __restrict__ deg, int n, int* __restrict__ incl,
    int* __restrict__ blocksums) {
  __shared__ int sm[1024];
  int t = threadIdx.x;
  int i = blockIdx.x * 1024 + t;
  sm[t] = (i < n) ? deg[i] : 0;
  __syncthreads();
  #pragma unroll
  for (int o = 1; o < 1024; o <<= 1) {
    int a = (t >= o) ? sm[t - o] : 0;
    __syncthreads();
    sm[t] += a;
    __syncthreads();
  }
  if (i < n) incl[i] = sm[t];
  if (t == 1023) blocksums[blockIdx.x] = sm[t];
}

__global__ __launch_bounds__(1024) void scan2_kernel(int* __restrict__ bs, int nb) {
  __shared__ int sm[1024];
  int t = threadIdx.x;
  sm[t] = (t < nb) ? bs[t] : 0;
  __syncthreads();
  #pragma unroll
  for (int o = 1; o < 1024; o <<= 1) {
    int a = (t >= o) ? sm[t - o] : 0;
    __syncthreads();
    sm[t] += a;
    __syncthreads();
  }
  if (t < nb) bs[t] = sm[t];
}

__global__ __launch_bounds__(1024) void scan3_kernel(
    const int* __restrict__ incl, const int* __restrict__ deg,
    const int* __restrict__ bs, int n, int* __restrict__ rowcur) {
  int i = blockIdx.x * 1024 + threadIdx.x;
  if (i >= n) return;
  int off = (blockIdx.x > 0) ? bs[blockIdx.x - 1] : 0;
  rowcur[i] = incl[i] - deg[i] + off;
}

__global__ __launch_bounds__(256) void scatter_kernel(
    const int* __restrict__ ei, int E, int ET, int* __restrict__ rowcur,
    int* __restrict__ csr_src) {
  int e = blockIdx.x * 256 + threadIdx.x;
  if (e >= ET) return;
  int s, d;
  if (e < E) { s = ei[e]; d = ei[E + e]; }
  else       { s = e - E; d = s; }
  int pos = atomicAdd(&rowcur[d], 1);
  csr_src[pos] = s;
}

// ---------- input layernorm over 64 features (wave per row) ----------
__global__ __launch_bounds__(256) void ln64_kernel(
    const float* __restrict__ x, const float* __restrict__ g,
    const float* __restrict__ b, float* __restrict__ y, int n) {
  int row = blockIdx.x * 4 + (threadIdx.x >> 6);
  int l = threadIdx.x & 63;
  if (row >= n) return;
  float v = x[(size_t)row * 64 + l];
  float s = v, sq = v * v;
  #pragma unroll
  for (int o = 32; o; o >>= 1) { s += __shfl_xor(s, o); sq += __shfl_xor(sq, o); }
  float mean = s * (1.f / 64.f);
  float var = sq * (1.f / 64.f) - mean * mean;
  float rstd = rsqrtf(var + 1e-5f);
  y[(size_t)row * 64 + l] = (v - mean) * rstd * g[l] + b[l];
}

// ---------- dual GEMM: YL = X@WL, YR = X@WR  (FOUT = 128 each) -------------
// 128-row tile; thread tile rows {r0..r0+3, r0+64..r0+67} x cols {c0..c0+3,
// c0+64..c0+67}; stride-4 float4 LDS addresses -> 2-way bank access (free).
template <int FIN>
__global__ __launch_bounds__(256, 3) void dual_gemm_kernel(
    const float* __restrict__ X, const float* __restrict__ WL,
    const float* __restrict__ WR, float* __restrict__ YL,
    float* __restrict__ YR, int nrows) {
  constexpr int TR = 128, KC = 32, XP = TR + 4;
  __shared__ float Xs[KC * XP];
  __shared__ float WsL[KC * 128];
  __shared__ float WsR[KC * 128];
  const int tid = threadIdx.x;
  const int row0 = blockIdx.x * TR;
  const int c0 = (tid & 15) * 4;
  const int r0 = (tid >> 4) * 4;

  float accL[8][8], accR[8][8];
  #pragma unroll
  for (int r = 0; r < 8; r++)
    #pragma unroll
    for (int c = 0; c < 8; c++) { accL[r][c] = 0.f; accR[r][c] = 0.f; }

  for (int k0 = 0; k0 < FIN; k0 += KC) {
    __syncthreads();
    // X staged transposed: Xs[k][r]
    for (int i = tid; i < TR * KC / 4; i += 256) {
      int r = i >> 3, kq = (i & 7) << 2;
      float4 v = make_float4(0.f, 0.f, 0.f, 0.f);
      if (row0 + r < nrows)
        v = *(const float4*)&X[(row0 + r) * FIN + k0 + kq];
      Xs[(kq + 0) * XP + r] = v.x;
      Xs[(kq + 1) * XP + r] = v.y;
      Xs[(kq + 2) * XP + r] = v.z;
      Xs[(kq + 3) * XP + r] = v.w;
    }
    // W staged row-major (pad-free)
    for (int i = tid; i < KC * 32; i += 256) {
      int k = i >> 5, c = (i & 31) << 2;
      *(float4*)&WsL[k * 128 + c] = *(const float4*)&WL[(k0 + k) * 128 + c];
      *(float4*)&WsR[k * 128 + c] = *(const float4*)&WR[(k0 + k) * 128 + c];
    }
    __syncthreads();
    #pragma unroll 2
    for (int k = 0; k < KC; k++) {
      float4 xa = *(const float4*)&Xs[k * XP + r0];
      float4 xb = *(const float4*)&Xs[k * XP + r0 + 64];
      float4 wla = *(const float4*)&WsL[k * 128 + c0];
      float4 wlb = *(const float4*)&WsL[k * 128 + c0 + 64];
      float4 wra = *(const float4*)&WsR[k * 128 + c0];
      float4 wrb = *(const float4*)&WsR[k * 128 + c0 + 64];
      float xh[8] = {xa.x, xa.y, xa.z, xa.w, xb.x, xb.y, xb.z, xb.w};
      float wl8[8] = {wla.x, wla.y, wla.z, wla.w, wlb.x, wlb.y, wlb.z, wlb.w};
      float wr8[8] = {wra.x, wra.y, wra.z, wra.w, wrb.x, wrb.y, wrb.z, wrb.w};
      #pragma unroll
      for (int r = 0; r < 8; r++)
        #pragma unroll
        for (int c = 0; c < 8; c++) {
          accL[r][c] += xh[r] * wl8[c];
          accR[r][c] += xh[r] * wr8[c];
        }
    }
  }
  #pragma unroll
  for (int rr = 0; rr < 8; rr++) {
    int row = row0 + ((rr < 4) ? (r0 + rr) : (64 + r0 + rr - 4));
    if (row >= nrows) continue;
    *(float4*)&YL[(size_t)row * 128 + c0] =
        make_float4(accL[rr][0], accL[rr][1], accL[rr][2], accL[rr][3]);
    *(float4*)&YL[(size_t)row * 128 + c0 + 64] =
        make_float4(accL[rr][4], accL[rr][5], accL[rr][6], accL[rr][7]);
    *(float4*)&YR[(size_t)row * 128 + c0] =
        make_float4(accR[rr][0], accR[rr][1], accR[rr][2], accR[rr][3]);
    *(float4*)&YR[(size_t)row * 128 + c0 + 64] =
        make_float4(accR[rr][4], accR[rr][5], accR[rr][6], accR[rr][7]);
  }
}

// ---------- dual head GEMM: YL = relu(X@W1+b1), YR = relu(X@W2+b2), 64 each -
__global__ __launch_bounds__(256, 4) void dual_head_kernel(
    const float* __restrict__ X, const float* __restrict__ W1,
    const float* __restrict__ b1, const float* __restrict__ W2,
    const float* __restrict__ b2, float* __restrict__ YL,
    float* __restrict__ YR, int nrows) {
  constexpr int FIN = 128, TR = 128, KC = 32, XP = TR + 4;
  __shared__ float Xs[KC * XP];
  __shared__ float Ws[KC * 128];  // cols 0-63 = W1, 64-127 = W2
  const int tid = threadIdx.x;
  const int row0 = blockIdx.x * TR;
  const int c0 = (tid & 15) * 4;
  const int r0 = (tid >> 4) * 4;

  float acc[8][8];  // cols 0-3: W1 c0.., 4-7: W2 c0..
  #pragma unroll
  for (int r = 0; r < 8; r++)
    #pragma unroll
    for (int c = 0; c < 8; c++) acc[r][c] = 0.f;

  for (int k0 = 0; k0 < FIN; k0 += KC) {
    __syncthreads();
    for (int i = tid; i < TR * KC / 4; i += 256) {
      int r = i >> 3, kq = (i & 7) << 2;
      float4 v = make_float4(0.f, 0.f, 0.f, 0.f);
      if (row0 + r < nrows)
        v = *(const float4*)&X[(row0 + r) * FIN + k0 + kq];
      Xs[(kq + 0) * XP + r] = v.x;
      Xs[(kq + 1) * XP + r] = v.y;
      Xs[(kq + 2) * XP + r] = v.z;
      Xs[(kq + 3) * XP + r] = v.w;
    }
    for (int i = tid; i < KC * 32; i += 256) {
      int k = i >> 5, c = (i & 31) << 2;
      float4 v = (c < 64) ? *(const float4*)&W1[(k0 + k) * 64 + c]
                          : *(const float4*)&W2[(k0 + k) * 64 + (c - 64)];
      *(float4*)&Ws[k * 128 + c] = v;
    }
    __syncthreads();
    #pragma unroll 2
    for (int k = 0; k < KC; k++) {
      float4 xa = *(const float4*)&Xs[k * XP + r0];
      float4 xb = *(const float4*)&Xs[k * XP + r0 + 64];
      float4 wa = *(const float4*)&Ws[k * 128 + c0];
      float4 wb = *(const float4*)&Ws[k * 128 + c0 + 64];
      float xh[8] = {xa.x, xa.y, xa.z, xa.w, xb.x, xb.y, xb.z, xb.w};
      float w8[8] = {wa.x, wa.y, wa.z, wa.w, wb.x, wb.y, wb.z, wb.w};
      #pragma unroll
      for (int r = 0; r < 8; r++)
        #pragma unroll
        for (int c = 0; c < 8; c++) acc[r][c] += xh[r] * w8[c];
    }
  }
  float4 ba = *(const float4*)&b1[c0];
  float4 bb = *(const float4*)&b2[c0];
  #pragma unroll
  for (int rr = 0; rr < 8; rr++) {
    int row = row0 + ((rr < 4) ? (r0 + rr) : (64 + r0 + rr - 4));
    if (row >= nrows) continue;
    float4 va = make_float4(fmaxf(acc[rr][0] + ba.x, 0.f),
                            fmaxf(acc[rr][1] + ba.y, 0.f),
                            fmaxf(acc[rr][2] + ba.z, 0.f),
                            fmaxf(acc[rr][3] + ba.w, 0.f));
    float4 vb = make_float4(fmaxf(acc[rr][4] + bb.x, 0.f),
                            fmaxf(acc[rr][5] + bb.y, 0.f),
                            fmaxf(acc[rr][6] + bb.z, 0.f),
                            fmaxf(acc[rr][7] + bb.w, 0.f));
    *(float4*)&YL[(size_t)row * 64 + c0] = va;
    *(float4*)&YR[(size_t)row * 64 + c0] = vb;
  }
}

// ---------- fused GAT layer -------------------------------------------------
// Wave per dst row; each 32-lane half processes its own edge stream.
// Lane ll owns channels 4ll..4ll+3. Plain softmax sums (logits bounded here),
// halves combine via xor-32 add. Streamed xr/res use nontemporal loads.
template <int H>
__global__ __launch_bounds__(256) void gat_fused_kernel(
    const float* __restrict__ xl, const float* __restrict__ xr,
    const int* __restrict__ csr_src, const int* __restrict__ row_end,
    const int* __restrict__ deg, const float* __restrict__ att,
    const float* __restrict__ res, const float* __restrict__ g,
    const float* __restrict__ b, float* __restrict__ y, int n,
    float resScale, int doRelu) {
  int row = blockIdx.x * 4 + (threadIdx.x >> 6);
  if (row >= n) return;
  int l = threadIdx.x & 63;
  int half = l >> 5;
  int ll = l & 31;
  int c = ll * 4;
  int end = row_end[row];
  int dg = deg[row];
  int start = end - dg;
  int cnt = (dg + 1 - half) >> 1;

  const int rofs = row * 512 + ll * 16;  // byte offset of this lane's chunk
  const f4v xrv = __builtin_nontemporal_load((const f4v*)((const char*)xr + rofs));
  const f4v av = *(const f4v*)&att[c];

  float s = 0.f;
  float a0 = 0.f, a1 = 0.f, a2 = 0.f, a3 = 0.f;

  int idx = start + half;
  f4v xn = {0.f, 0.f, 0.f, 0.f};
  if (cnt > 0) {
    int s0 = csr_src[idx];
    xn = *(const f4v*)((const char*)xl + s0 * 512 + ll * 16);
  }
  for (int i = 0; i < cnt; i++) {
    f4v xv = xn;
    if (i + 1 < cnt) {
      int sn = csr_src[idx + 2];
      xn = *(const f4v*)((const char*)xl + sn * 512 + ll * 16);
    }
    idx += 2;
    float v0 = xv.x + xrv.x; v0 = v0 > 0.f ? v0 : NEG_SLOPE * v0;
    float v1 = xv.y + xrv.y; v1 = v1 > 0.f ? v1 : NEG_SLOPE * v1;
    float v2 = xv.z + xrv.z; v2 = v2 > 0.f ? v2 : NEG_SLOPE * v2;
    float v3 = xv.w + xrv.w; v3 = v3 > 0.f ? v3 : NEG_SLOPE * v3;
    float p = v0 * av.x + v1 * av.y + v2 * av.z + v3 * av.w;
    if constexpr (H == 1) {
      #pragma unroll
      for (int o = 16; o; o >>= 1) p += __shfl_xor(p, o);
    } else {  // H=4: head group = 8 lanes (32 channels)
      #pragma unroll
      for (int o = 4; o; o >>= 1) p += __shfl_xor(p, o);
    }
    float e = __expf(p);
    s += e;
    a0 += e * xv.x; a1 += e * xv.y; a2 += e * xv.z; a3 += e * xv.w;
  }
  s  += __shfl_xor(s, 32);
  a0 += __shfl_xor(a0, 32);
  a1 += __shfl_xor(a1, 32);
  a2 += __shfl_xor(a2, 32);
  a3 += __shfl_xor(a3, 32);

  float inv = 1.f / s;
  float o0 = a0 * inv, o1 = a1 * inv, o2 = a2 * inv, o3 = a3 * inv;

  float sum = o0 + o1 + o2 + o3;
  float sq = o0 * o0 + o1 * o1 + o2 * o2 + o3 * o3;
  #pragma unroll
  for (int o = 16; o; o >>= 1) { sum += __shfl_xor(sum, o); sq += __shfl_xor(sq, o); }
  float mean = sum * (1.f / 128.f);
  float var = sq * (1.f / 128.f) - mean * mean;
  float rstd = rsqrtf(var + 1e-5f);
  const f4v gv = *(const f4v*)&g[c];
  const f4v bv = *(const f4v*)&b[c];
  float r0 = (o0 - mean) * rstd * gv.x + bv.x;
  float r1 = (o1 - mean) * rstd * gv.y + bv.y;
  float r2 = (o2 - mean) * rstd * gv.z + bv.z;
  float r3 = (o3 - mean) * rstd * gv.w + bv.w;
  if (res) {
    const f4v rv = __builtin_nontemporal_load((const f4v*)((const char*)res + rofs));
    r0 += resScale * rv.x; r1 += resScale * rv.y;
    r2 += resScale * rv.z; r3 += resScale * rv.w;
  }
  if (doRelu) {
    r0 = fmaxf(r0, 0.f); r1 = fmaxf(r1, 0.f);
    r2 = fmaxf(r2, 0.f); r3 = fmaxf(r3, 0.f);
  }
  if (half == 0) {
    f4v o = {r0, r1, r2, r3};
    *(f4v*)((char*)y + rofs) = o;
  }
}

// ---------- final heads ----------
__global__ __launch_bounds__(256) void head_out_kernel(
    const float* __restrict__ t_rtt, const float* __restrict__ t_ret,
    const float* __restrict__ w2r, const float* __restrict__ b2r,
    const float* __restrict__ w2e, const float* __restrict__ b2e,
    float* __restrict__ out, int n) {
  int row = blockIdx.x * 4 + (threadIdx.x >> 6);
  int l = threadIdx.x & 63;
  if (row >= n) return;
  float a = t_rtt[(size_t)row * 64 + l] * w2r[l];
  float c = t_ret[(size_t)row * 64 + l] * w2e[l];
  #pragma unroll
  for (int o = 32; o; o >>= 1) { a += __shfl_xor(a, o); c += __shfl_xor(c, o); }
  if (l == 0) {
    out[(size_t)row * 2 + 0] = a + b2r[0];
    out[(size_t)row * 2 + 1] = c + b2e[0];
  }
}

// ---------- launch ----------
extern "C" void kernel_launch(void* const* d_in, const int* in_sizes, int n_in,
                              void* d_out, int out_size, void* d_ws,
                              size_t ws_size, hipStream_t stream) {
  const float* x       = (const float*)d_in[0];
  const int*   ei      = (const int*)d_in[1];
  const float* ln_in_g = (const float*)d_in[2];
  const float* ln_in_b = (const float*)d_in[3];
  const float* w_l1    = (const float*)d_in[4];
  const float* w_r1    = (const float*)d_in[5];
  const float* att1    = (const float*)d_in[6];
  const float* ln1_g   = (const float*)d_in[7];
  const float* ln1_b   = (const float*)d_in[8];
  const float* w_l2    = (const float*)d_in[9];
  const float* w_r2    = (const float*)d_in[10];
  const float* att2    = (const float*)d_in[11];
  const float* ln2_g   = (const float*)d_in[12];
  const float* ln2_b   = (const float*)d_in[13];
  const float* w_l3    = (const float*)d_in[14];
  const float* w_r3    = (const float*)d_in[15];
  const float* att3    = (const float*)d_in[16];
  const float* ln3_g   = (const float*)d_in[17];
  const float* ln3_b   = (const float*)d_in[18];
  const float* rtt_w1  = (const float*)d_in[19];
  const float* rtt_b1  = (const float*)d_in[20];
  const float* rtt_w2  = (const float*)d_in[21];
  const float* rtt_b2  = (const float*)d_in[22];
  const float* ret_w1  = (const float*)d_in[23];
  const float* ret_b1  = (const float*)d_in[24];
  const float* ret_w2  = (const float*)d_in[25];
  const float* ret_b2  = (const float*)d_in[26];

  const int N = in_sizes[0] / 64;
  const int E = in_sizes[1] / 2;
  const int ET = E + N;
  const size_t NF = (size_t)N * 128;

  float* A = (float*)d_ws;            // node features h / residual
  float* B = A + NF;                  // xl (later rtt hidden)
  float* C = B + NF;                  // xr (later ret hidden)
  int* deg     = (int*)(C + NF);      // N
  int* rowcur  = deg + N;             // N (becomes row_end after scatter)
  int* incl    = rowcur + N;          // N
  int* bsums   = incl + N;            // 1024
  int* csr_src = bsums + 1024;        // ET

  float* out = (float*)d_out;

  const int rowBlocks  = (N + 3) / 4;
  const int gemmBlocks = (N + 127) / 128;
  const int NB = (N + 1023) / 1024;

  // ---- CSR build (by dst) ----
  fill_ones_kernel<<<(N + 255) / 256, 256, 0, stream>>>(deg, N);
  degree_count_kernel<<<(E + 255) / 256, 256, 0, stream>>>(ei, E, deg);
  scan1_kernel<<<NB, 1024, 0, stream>>>(deg, N, incl, bsums);
  scan2_kernel<<<1, 1024, 0, stream>>>(bsums, NB);
  scan3_kernel<<<NB, 1024, 0, stream>>>(incl, deg, bsums, N, rowcur);
  scatter_kernel<<<(ET + 255) / 256, 256, 0, stream>>>(ei, E, ET, rowcur, csr_src);

  // ---- input layernorm ----
  ln64_kernel<<<rowBlocks, 256, 0, stream>>>(x, ln_in_g, ln_in_b, A, N);

  // ---- layer 0: 64 -> 128, 4 heads, no residual, relu ----
  dual_gemm_kernel<64><<<gemmBlocks, 256, 0, stream>>>(A, w_l1, w_r1, B, C, N);
  gat_fused_kernel<4><<<rowBlocks, 256, 0, stream>>>(
      B, C, csr_src, rowcur, deg, att1, nullptr, ln1_g, ln1_b, A, N, 0.f, 1);

  // ---- layer 1: 128 -> 128, 4 heads, residual 0.1, relu ----
  dual_gemm_kernel<128><<<gemmBlocks, 256, 0, stream>>>(A, w_l2, w_r2, B, C, N);
  gat_fused_kernel<4><<<rowBlocks, 256, 0, stream>>>(
      B, C, csr_src, rowcur, deg, att2, A, ln2_g, ln2_b, A, N, 0.1f, 1);

  // ---- layer 2: 128 -> 128, 1 head, residual 0.1, no relu ----
  dual_gemm_kernel<128><<<gemmBlocks, 256, 0, stream>>>(A, w_l3, w_r3, B, C, N);
  gat_fused_kernel<1><<<rowBlocks, 256, 0, stream>>>(
      B, C, csr_src, rowcur, deg, att3, A, ln3_g, ln3_b, A, N, 0.1f, 0);

  // ---- prediction heads (fused rtt+ret) ----
  dual_head_kernel<<<gemmBlocks, 256, 0, stream>>>(A, rtt_w1, rtt_b1, ret_w1,
                                                   ret_b1, B, C, N);
  head_out_kernel<<<rowBlocks, 256, 0, stream>>>(B, C, rtt_w2, rtt_b2, ret_w2,
                                                 ret_b2, out, N);
}

// Round 5
// 809.233 us; speedup vs baseline: 3.3097x; 1.0496x over previous
//
#include <hip/hip_runtime.h>
#include <cstdint>
#include <cstddef>

#define NEG_SLOPE 0.2f

typedef float f4v __attribute__((ext_vector_type(4)));

// ---------- CSR build ----------

__global__ __launch_bounds__(256) void fill_ones_kernel(int* __restrict__ p, int n) {
  int i = blockIdx.x * 256 + threadIdx.x;
  if (i < n) p[i] = 1;  // self-loop contributes degree 1
}

__global__ __launch_bounds__(256) void degree_count_kernel(
    const int* __restrict__ ei, int E, int* __restrict__ deg) {
  int e = blockIdx.x * 256 + threadIdx.x;
  if (e < E) atomicAdd(&deg[ei[E + e]], 1);
}

__global__ __launch_bounds__(1024) void scan1_kernel(
    const int* __restrict__ deg, int n, int* __restrict__ incl,
    int* __restrict__ blocksums) {
  __shared__ int sm[1024];
  int t = threadIdx.x;
  int i = blockIdx.x * 1024 + t;
  sm[t] = (i < n) ? deg[i] : 0;
  __syncthreads();
  #pragma unroll
  for (int o = 1; o < 1024; o <<= 1) {
    int a = (t >= o) ? sm[t - o] : 0;
    __syncthreads();
    sm[t] += a;
    __syncthreads();
  }
  if (i < n) incl[i] = sm[t];
  if (t == 1023) blocksums[blockIdx.x] = sm[t];
}

__global__ __launch_bounds__(1024) void scan2_kernel(int* __restrict__ bs, int nb) {
  __shared__ int sm[1024];
  int t = threadIdx.x;
  sm[t] = (t < nb) ? bs[t] : 0;
  __syncthreads();
  #pragma unroll
  for (int o = 1; o < 1024; o <<= 1) {
    int a = (t >= o) ? sm[t - o] : 0;
    __syncthreads();
    sm[t] += a;
    __syncthreads();
  }
  if (t < nb) bs[t] = sm[t];
}

__global__ __launch_bounds__(1024) void scan3_kernel(
    const int* __restrict__ incl, const int* __restrict__ deg,
    const int* __restrict__ bs, int n, int* __restrict__ rowcur) {
  int i = blockIdx.x * 1024 + threadIdx.x;
  if (i >= n) return;
  int off = (blockIdx.x > 0) ? bs[blockIdx.x - 1] : 0;
  rowcur[i] = incl[i] - deg[i] + off;
}

__global__ __launch_bounds__(256) void scatter_kernel(
    const int* __restrict__ ei, int E, int ET, int* __restrict__ rowcur,
    int* __restrict__ csr_src) {
  int e = blockIdx.x * 256 + threadIdx.x;
  if (e >= ET) return;
  int s, d;
  if (e < E) { s = ei[e]; d = ei[E + e]; }
  else       { s = e - E; d = s; }
  int pos = atomicAdd(&rowcur[d], 1);
  csr_src[pos] = s;
}

// ---------- input layernorm over 64 features (wave per row) ----------
__global__ __launch_bounds__(256) void ln64_kernel(
    const float* __restrict__ x, const float* __restrict__ g,
    const float* __restrict__ b, float* __restrict__ y, int n) {
  int row = blockIdx.x * 4 + (threadIdx.x >> 6);
  int l = threadIdx.x & 63;
  if (row >= n) return;
  float v = x[(size_t)row * 64 + l];
  float s = v, sq = v * v;
  #pragma unroll
  for (int o = 32; o; o >>= 1) { s += __shfl_xor(s, o); sq += __shfl_xor(sq, o); }
  float mean = s * (1.f / 64.f);
  float var = sq * (1.f / 64.f) - mean * mean;
  float rstd = rsqrtf(var + 1e-5f);
  y[(size_t)row * 64 + l] = (v - mean) * rstd * g[l] + b[l];
}

// ---------- GEMM (L/R split by blockIdx.y): Y = X@W, FOUT=128 --------------
// 128-row tile, 256 threads, thread tile = rows {r0..r0+3, r0+64..r0+67} x
// cols {c0..c0+3, c0+64..c0+67}. LDS 33.3 KB -> 4 blocks/CU (16 waves,
// 4 waves/SIMD). Inner-loop LDS reads: stride-4 float4 -> 2-way (free).
template <int FIN>
__global__ __launch_bounds__(256, 4) void gemm_lr_kernel(
    const float* __restrict__ X, const float* __restrict__ WL,
    const float* __restrict__ WR, float* __restrict__ YL,
    float* __restrict__ YR, int nrows) {
  constexpr int TR = 128, KC = 32, XP = TR + 4;
  __shared__ float Xs[KC * XP];
  __shared__ float Ws[KC * 128];
  const float* W = blockIdx.y ? WR : WL;
  float* Y = blockIdx.y ? YR : YL;
  const int tid = threadIdx.x;
  const int row0 = blockIdx.x * TR;
  const int c0 = (tid & 15) * 4;
  const int r0 = (tid >> 4) * 4;

  float acc[8][8];
  #pragma unroll
  for (int r = 0; r < 8; r++)
    #pragma unroll
    for (int c = 0; c < 8; c++) acc[r][c] = 0.f;

  for (int k0 = 0; k0 < FIN; k0 += KC) {
    __syncthreads();
    // X staged transposed: Xs[k][r]
    for (int i = tid; i < TR * KC / 4; i += 256) {
      int r = i >> 3, kq = (i & 7) << 2;
      float4 v = make_float4(0.f, 0.f, 0.f, 0.f);
      if (row0 + r < nrows)
        v = *(const float4*)&X[(row0 + r) * FIN + k0 + kq];
      Xs[(kq + 0) * XP + r] = v.x;
      Xs[(kq + 1) * XP + r] = v.y;
      Xs[(kq + 2) * XP + r] = v.z;
      Xs[(kq + 3) * XP + r] = v.w;
    }
    // W staged row-major
    for (int i = tid; i < KC * 32; i += 256) {
      int k = i >> 5, c = (i & 31) << 2;
      *(float4*)&Ws[k * 128 + c] = *(const float4*)&W[(k0 + k) * 128 + c];
    }
    __syncthreads();
    #pragma unroll 4
    for (int k = 0; k < KC; k++) {
      float4 xa = *(const float4*)&Xs[k * XP + r0];
      float4 xb = *(const float4*)&Xs[k * XP + r0 + 64];
      float4 wa = *(const float4*)&Ws[k * 128 + c0];
      float4 wb = *(const float4*)&Ws[k * 128 + c0 + 64];
      float xh[8] = {xa.x, xa.y, xa.z, xa.w, xb.x, xb.y, xb.z, xb.w};
      float w8[8] = {wa.x, wa.y, wa.z, wa.w, wb.x, wb.y, wb.z, wb.w};
      #pragma unroll
      for (int r = 0; r < 8; r++)
        #pragma unroll
        for (int c = 0; c < 8; c++) acc[r][c] += xh[r] * w8[c];
    }
  }
  #pragma unroll
  for (int rr = 0; rr < 8; rr++) {
    int row = row0 + ((rr < 4) ? (r0 + rr) : (64 + r0 + rr - 4));
    if (row >= nrows) continue;
    *(float4*)&Y[(size_t)row * 128 + c0] =
        make_float4(acc[rr][0], acc[rr][1], acc[rr][2], acc[rr][3]);
    *(float4*)&Y[(size_t)row * 128 + c0 + 64] =
        make_float4(acc[rr][4], acc[rr][5], acc[rr][6], acc[rr][7]);
  }
}

// ---------- head GEMM (rtt/ret split by blockIdx.y): Y=relu(X@W+b), 64 cols -
__global__ __launch_bounds__(256, 6) void head_lr_kernel(
    const float* __restrict__ X, const float* __restrict__ W1,
    const float* __restrict__ b1, const float* __restrict__ W2,
    const float* __restrict__ b2, float* __restrict__ YL,
    float* __restrict__ YR, int nrows) {
  constexpr int FIN = 128, TR = 128, KC = 32, XP = TR + 4;
  __shared__ float Xs[KC * XP];
  __shared__ float Ws[KC * 64];
  const float* W = blockIdx.y ? W2 : W1;
  const float* bias = blockIdx.y ? b2 : b1;
  float* Y = blockIdx.y ? YR : YL;
  const int tid = threadIdx.x;
  const int row0 = blockIdx.x * TR;
  const int c0 = (tid & 15) * 4;
  const int r0 = (tid >> 4) * 4;

  float acc[8][4];
  #pragma unroll
  for (int r = 0; r < 8; r++)
    #pragma unroll
    for (int c = 0; c < 4; c++) acc[r][c] = 0.f;

  for (int k0 = 0; k0 < FIN; k0 += KC) {
    __syncthreads();
    for (int i = tid; i < TR * KC / 4; i += 256) {
      int r = i >> 3, kq = (i & 7) << 2;
      float4 v = make_float4(0.f, 0.f, 0.f, 0.f);
      if (row0 + r < nrows)
        v = *(const float4*)&X[(row0 + r) * FIN + k0 + kq];
      Xs[(kq + 0) * XP + r] = v.x;
      Xs[(kq + 1) * XP + r] = v.y;
      Xs[(kq + 2) * XP + r] = v.z;
      Xs[(kq + 3) * XP + r] = v.w;
    }
    for (int i = tid; i < KC * 16; i += 256) {
      int k = i >> 4, c = (i & 15) << 2;
      *(float4*)&Ws[k * 64 + c] = *(const float4*)&W[(k0 + k) * 64 + c];
    }
    __syncthreads();
    #pragma unroll 4
    for (int k = 0; k < KC; k++) {
      float4 xa = *(const float4*)&Xs[k * XP + r0];
      float4 xb = *(const float4*)&Xs[k * XP + r0 + 64];
      float4 wa = *(const float4*)&Ws[k * 64 + c0];
      float xh[8] = {xa.x, xa.y, xa.z, xa.w, xb.x, xb.y, xb.z, xb.w};
      #pragma unroll
      for (int r = 0; r < 8; r++) {
        acc[r][0] += xh[r] * wa.x;
        acc[r][1] += xh[r] * wa.y;
        acc[r][2] += xh[r] * wa.z;
        acc[r][3] += xh[r] * wa.w;
      }
    }
  }
  float4 bb = *(const float4*)&bias[c0];
  #pragma unroll
  for (int rr = 0; rr < 8; rr++) {
    int row = row0 + ((rr < 4) ? (r0 + rr) : (64 + r0 + rr - 4));
    if (row >= nrows) continue;
    *(float4*)&Y[(size_t)row * 64 + c0] =
        make_float4(fmaxf(acc[rr][0] + bb.x, 0.f),
                    fmaxf(acc[rr][1] + bb.y, 0.f),
                    fmaxf(acc[rr][2] + bb.z, 0.f),
                    fmaxf(acc[rr][3] + bb.w, 0.f));
  }
}

// ---------- fused GAT layer -------------------------------------------------
template <int H>
__global__ __launch_bounds__(256) void gat_fused_kernel(
    const float* __restrict__ xl, const float* __restrict__ xr,
    const int* __restrict__ csr_src, const int* __restrict__ row_end,
    const int* __restrict__ deg, const float* __restrict__ att,
    const float* __restrict__ res, const float* __restrict__ g,
    const float* __restrict__ b, float* __restrict__ y, int n,
    float resScale, int doRelu) {
  int row = blockIdx.x * 4 + (threadIdx.x >> 6);
  if (row >= n) return;
  int l = threadIdx.x & 63;
  int half = l >> 5;
  int ll = l & 31;
  int c = ll * 4;
  int end = row_end[row];
  int dg = deg[row];
  int start = end - dg;
  int cnt = (dg + 1 - half) >> 1;

  const int rofs = row * 512 + ll * 16;  // byte offset of this lane's chunk
  const f4v xrv = __builtin_nontemporal_load((const f4v*)((const char*)xr + rofs));
  const f4v av = *(const f4v*)&att[c];

  float s = 0.f;
  float a0 = 0.f, a1 = 0.f, a2 = 0.f, a3 = 0.f;

  int idx = start + half;
  f4v xn = {0.f, 0.f, 0.f, 0.f};
  if (cnt > 0) {
    int s0 = csr_src[idx];
    xn = *(const f4v*)((const char*)xl + s0 * 512 + ll * 16);
  }
  for (int i = 0; i < cnt; i++) {
    f4v xv = xn;
    if (i + 1 < cnt) {
      int sn = csr_src[idx + 2];
      xn = *(const f4v*)((const char*)xl + sn * 512 + ll * 16);
    }
    idx += 2;
    float v0 = xv.x + xrv.x; v0 = v0 > 0.f ? v0 : NEG_SLOPE * v0;
    float v1 = xv.y + xrv.y; v1 = v1 > 0.f ? v1 : NEG_SLOPE * v1;
    float v2 = xv.z + xrv.z; v2 = v2 > 0.f ? v2 : NEG_SLOPE * v2;
    float v3 = xv.w + xrv.w; v3 = v3 > 0.f ? v3 : NEG_SLOPE * v3;
    float p = v0 * av.x + v1 * av.y + v2 * av.z + v3 * av.w;
    if constexpr (H == 1) {
      #pragma unroll
      for (int o = 16; o; o >>= 1) p += __shfl_xor(p, o);
    } else {  // H=4: head group = 8 lanes (32 channels)
      #pragma unroll
      for (int o = 4; o; o >>= 1) p += __shfl_xor(p, o);
    }
    float e = __expf(p);
    s += e;
    a0 += e * xv.x; a1 += e * xv.y; a2 += e * xv.z; a3 += e * xv.w;
  }
  s  += __shfl_xor(s, 32);
  a0 += __shfl_xor(a0, 32);
  a1 += __shfl_xor(a1, 32);
  a2 += __shfl_xor(a2, 32);
  a3 += __shfl_xor(a3, 32);

  float inv = 1.f / s;
  float o0 = a0 * inv, o1 = a1 * inv, o2 = a2 * inv, o3 = a3 * inv;

  float sum = o0 + o1 + o2 + o3;
  float sq = o0 * o0 + o1 * o1 + o2 * o2 + o3 * o3;
  #pragma unroll
  for (int o = 16; o; o >>= 1) { sum += __shfl_xor(sum, o); sq += __shfl_xor(sq, o); }
  float mean = sum * (1.f / 128.f);
  float var = sq * (1.f / 128.f) - mean * mean;
  float rstd = rsqrtf(var + 1e-5f);
  const f4v gv = *(const f4v*)&g[c];
  const f4v bv = *(const f4v*)&b[c];
  float r0 = (o0 - mean) * rstd * gv.x + bv.x;
  float r1 = (o1 - mean) * rstd * gv.y + bv.y;
  float r2 = (o2 - mean) * rstd * gv.z + bv.z;
  float r3 = (o3 - mean) * rstd * gv.w + bv.w;
  if (res) {
    const f4v rv = __builtin_nontemporal_load((const f4v*)((const char*)res + rofs));
    r0 += resScale * rv.x; r1 += resScale * rv.y;
    r2 += resScale * rv.z; r3 += resScale * rv.w;
  }
  if (doRelu) {
    r0 = fmaxf(r0, 0.f); r1 = fmaxf(r1, 0.f);
    r2 = fmaxf(r2, 0.f); r3 = fmaxf(r3, 0.f);
  }
  if (half == 0) {
    f4v o = {r0, r1, r2, r3};
    *(f4v*)((char*)y + rofs) = o;
  }
}

// ---------- final heads ----------
__global__ __launch_bounds__(256) void head_out_kernel(
    const float* __restrict__ t_rtt, const float* __restrict__ t_ret,
    const float* __restrict__ w2r, const float* __restrict__ b2r,
    const float* __restrict__ w2e, const float* __restrict__ b2e,
    float* __restrict__ out, int n) {
  int row = blockIdx.x * 4 + (threadIdx.x >> 6);
  int l = threadIdx.x & 63;
  if (row >= n) return;
  float a = t_rtt[(size_t)row * 64 + l] * w2r[l];
  float c = t_ret[(size_t)row * 64 + l] * w2e[l];
  #pragma unroll
  for (int o = 32; o; o >>= 1) { a += __shfl_xor(a, o); c += __shfl_xor(c, o); }
  if (l == 0) {
    out[(size_t)row * 2 + 0] = a + b2r[0];
    out[(size_t)row * 2 + 1] = c + b2e[0];
  }
}

// ---------- launch ----------
extern "C" void kernel_launch(void* const* d_in, const int* in_sizes, int n_in,
                              void* d_out, int out_size, void* d_ws,
                              size_t ws_size, hipStream_t stream) {
  const float* x       = (const float*)d_in[0];
  const int*   ei      = (const int*)d_in[1];
  const float* ln_in_g = (const float*)d_in[2];
  const float* ln_in_b = (const float*)d_in[3];
  const float* w_l1    = (const float*)d_in[4];
  const float* w_r1    = (const float*)d_in[5];
  const float* att1    = (const float*)d_in[6];
  const float* ln1_g   = (const float*)d_in[7];
  const float* ln1_b   = (const float*)d_in[8];
  const float* w_l2    = (const float*)d_in[9];
  const float* w_r2    = (const float*)d_in[10];
  const float* att2    = (const float*)d_in[11];
  const float* ln2_g   = (const float*)d_in[12];
  const float* ln2_b   = (const float*)d_in[13];
  const float* w_l3    = (const float*)d_in[14];
  const float* w_r3    = (const float*)d_in[15];
  const float* att3    = (const float*)d_in[16];
  const float* ln3_g   = (const float*)d_in[17];
  const float* ln3_b   = (const float*)d_in[18];
  const float* rtt_w1  = (const float*)d_in[19];
  const float* rtt_b1  = (const float*)d_in[20];
  const float* rtt_w2  = (const float*)d_in[21];
  const float* rtt_b2  = (const float*)d_in[22];
  const float* ret_w1  = (const float*)d_in[23];
  const float* ret_b1  = (const float*)d_in[24];
  const float* ret_w2  = (const float*)d_in[25];
  const float* ret_b2  = (const float*)d_in[26];

  const int N = in_sizes[0] / 64;
  const int E = in_sizes[1] / 2;
  const int ET = E + N;
  const size_t NF = (size_t)N * 128;

  float* A = (float*)d_ws;            // node features h / residual
  float* B = A + NF;                  // xl (later rtt hidden)
  float* C = B + NF;                  // xr (later ret hidden)
  int* deg     = (int*)(C + NF);      // N
  int* rowcur  = deg + N;             // N (becomes row_end after scatter)
  int* incl    = rowcur + N;          // N
  int* bsums   = incl + N;            // 1024
  int* csr_src = bsums + 1024;        // ET

  float* out = (float*)d_out;

  const int rowBlocks  = (N + 3) / 4;
  const int gemmBlocks = (N + 127) / 128;
  const int NB = (N + 1023) / 1024;
  dim3 gemmGrid(gemmBlocks, 2);

  // ---- CSR build (by dst) ----
  fill_ones_kernel<<<(N + 255) / 256, 256, 0, stream>>>(deg, N);
  degree_count_kernel<<<(E + 255) / 256, 256, 0, stream>>>(ei, E, deg);
  scan1_kernel<<<NB, 1024, 0, stream>>>(deg, N, incl, bsums);
  scan2_kernel<<<1, 1024, 0, stream>>>(bsums, NB);
  scan3_kernel<<<NB, 1024, 0, stream>>>(incl, deg, bsums, N, rowcur);
  scatter_kernel<<<(ET + 255) / 256, 256, 0, stream>>>(ei, E, ET, rowcur, csr_src);

  // ---- input layernorm ----
  ln64_kernel<<<rowBlocks, 256, 0, stream>>>(x, ln_in_g, ln_in_b, A, N);

  // ---- layer 0: 64 -> 128, 4 heads, no residual, relu ----
  gemm_lr_kernel<64><<<gemmGrid, 256, 0, stream>>>(A, w_l1, w_r1, B, C, N);
  gat_fused_kernel<4><<<rowBlocks, 256, 0, stream>>>(
      B, C, csr_src, rowcur, deg, att1, nullptr, ln1_g, ln1_b, A, N, 0.f, 1);

  // ---- layer 1: 128 -> 128, 4 heads, residual 0.1, relu ----
  gemm_lr_kernel<128><<<gemmGrid, 256, 0, stream>>>(A, w_l2, w_r2, B, C, N);
  gat_fused_kernel<4><<<rowBlocks, 256, 0, stream>>>(
      B, C, csr_src, rowcur, deg, att2, A, ln2_g, ln2_b, A, N, 0.1f, 1);

  // ---- layer 2: 128 -> 128, 1 head, residual 0.1, no relu ----
  gemm_lr_kernel<128><<<gemmGrid, 256, 0, stream>>>(A, w_l3, w_r3, B, C, N);
  gat_fused_kernel<1><<<rowBlocks, 256, 0, stream>>>(
      B, C, csr_src, rowcur, deg, att3, A, ln3_g, ln3_b, A, N, 0.1f, 0);

  // ---- prediction heads (rtt/ret split across blockIdx.y) ----
  head_lr_kernel<<<gemmGrid, 256, 0, stream>>>(A, rtt_w1, rtt_b1, ret_w1,
                                               ret_b1, B, C, N);
  head_out_kernel<<<rowBlocks, 256, 0, stream>>>(B, C, rtt_w2, rtt_b2, ret_w2,
                                                 ret_b2, out, N);
}

// Round 6
// 693.560 us; speedup vs baseline: 3.8617x; 1.1668x over previous
//
#include <hip/hip_runtime.h>
#include <hip/hip_bf16.h>
#include <cstdint>
#include <cstddef>

#define NEG_SLOPE 0.2f

typedef float f4v __attribute__((ext_vector_type(4)));
typedef short short8 __attribute__((ext_vector_type(8)));
typedef float f32x4 __attribute__((ext_vector_type(4)));

// fp32 -> (bf16 hi, bf16 lo): hi = truncate-to-bf16 (exact float),
// lo = RN-bf16(x - hi). hh+hl+lh MFMA reconstructs x*w to ~2^-16 rel.
__device__ __forceinline__ void cvt_hilo(float v, short& h, short& l) {
  unsigned u = __builtin_bit_cast(unsigned, v);
  h = (short)(u >> 16);
  float hif = __builtin_bit_cast(float, u & 0xFFFF0000u);
  l = __builtin_bit_cast(short, __float2bfloat16(v - hif));
}

// ---------- CSR build ----------

__global__ __launch_bounds__(256) void fill_ones_kernel(int* __restrict__ p, int n) {
  int i = blockIdx.x * 256 + threadIdx.x;
  if (i < n) p[i] = 1;  // self-loop contributes degree 1
}

__global__ __launch_bounds__(256) void degree_count_kernel(
    const int* __restrict__ ei, int E, int* __restrict__ deg) {
  int e = blockIdx.x * 256 + threadIdx.x;
  if (e < E) atomicAdd(&deg[ei[E + e]], 1);
}

__global__ __launch_bounds__(1024) void scan1_kernel(
    const int* __restrict__ deg, int n, int* __restrict__ incl,
    int* __restrict__ blocksums) {
  __shared__ int sm[1024];
  int t = threadIdx.x;
  int i = blockIdx.x * 1024 + t;
  sm[t] = (i < n) ? deg[i] : 0;
  __syncthreads();
  #pragma unroll
  for (int o = 1; o < 1024; o <<= 1) {
    int a = (t >= o) ? sm[t - o] : 0;
    __syncthreads();
    sm[t] += a;
    __syncthreads();
  }
  if (i < n) incl[i] = sm[t];
  if (t == 1023) blocksums[blockIdx.x] = sm[t];
}

__global__ __launch_bounds__(1024) void scan2_kernel(int* __restrict__ bs, int nb) {
  __shared__ int sm[1024];
  int t = threadIdx.x;
  sm[t] = (t < nb) ? bs[t] : 0;
  __syncthreads();
  #pragma unroll
  for (int o = 1; o < 1024; o <<= 1) {
    int a = (t >= o) ? sm[t - o] : 0;
    __syncthreads();
    sm[t] += a;
    __syncthreads();
  }
  if (t < nb) bs[t] = sm[t];
}

__global__ __launch_bounds__(1024) void scan3_kernel(
    const int* __restrict__ incl, const int* __restrict__ deg,
    const int* __restrict__ bs, int n, int* __restrict__ rowcur) {
  int i = blockIdx.x * 1024 + threadIdx.x;
  if (i >= n) return;
  int off = (blockIdx.x > 0) ? bs[blockIdx.x - 1] : 0;
  rowcur[i] = incl[i] - deg[i] + off;
}

__global__ __launch_bounds__(256) void scatter_kernel(
    const int* __restrict__ ei, int E, int ET, int* __restrict__ rowcur,
    int* __restrict__ csr_src) {
  int e = blockIdx.x * 256 + threadIdx.x;
  if (e >= ET) return;
  int s, d;
  if (e < E) { s = ei[e]; d = ei[E + e]; }
  else       { s = e - E; d = s; }
  int pos = atomicAdd(&rowcur[d], 1);
  csr_src[pos] = s;
}

// ---------- input layernorm over 64 features (wave per row) ----------
__global__ __launch_bounds__(256) void ln64_kernel(
    const float* __restrict__ x, const float* __restrict__ g,
    const float* __restrict__ b, float* __restrict__ y, int n) {
  int row = blockIdx.x * 4 + (threadIdx.x >> 6);
  int l = threadIdx.x & 63;
  if (row >= n) return;
  float v = x[(size_t)row * 64 + l];
  float s = v, sq = v * v;
  #pragma unroll
  for (int o = 32; o; o >>= 1) { s += __shfl_xor(s, o); sq += __shfl_xor(sq, o); }
  float mean = s * (1.f / 64.f);
  float var = sq * (1.f / 64.f) - mean * mean;
  float rstd = rsqrtf(var + 1e-5f);
  y[(size_t)row * 64 + l] = (v - mean) * rstd * g[l] + b[l];
}

// ---------- W -> MFMA B-fragment layout (hi/lo bf16) ----------
// out[seg] layout: elem i = [chunk c][tile t][lane][j]; value = W[k][n] with
// k = c*32 + (lane>>4)*8 + j, n = t*16 + (lane&15). hi at [i], lo at [i+sz].
struct PrepArgs {
  const float* w[8];
  short* o[8];
  int fout[8];
  int cum[9];
};

__global__ __launch_bounds__(256) void prep_w_kernel(PrepArgs pa) {
  int i = blockIdx.x * 256 + threadIdx.x;
  if (i >= pa.cum[8]) return;
  int s = 0;
  while (i >= pa.cum[s + 1]) s++;
  int li = i - pa.cum[s];
  int FOUT = pa.fout[s];
  int NT = FOUT >> 4;
  int sz = pa.cum[s + 1] - pa.cum[s];
  int c = li / (NT * 512);
  int r1 = li % (NT * 512);
  int t = r1 >> 9;
  int e = r1 & 511;
  int lane = e >> 3, j = e & 7;
  int k = c * 32 + (lane >> 4) * 8 + j;
  int n = t * 16 + (lane & 15);
  float v = pa.w[s][k * FOUT + n];
  short h, l;
  cvt_hilo(v, h, l);
  pa.o[s][li] = h;
  pa.o[s][li + sz] = l;
}

// ---------- MFMA GEMM: Y = X @ W (split-bf16, no LDS, no barriers) ---------
// Block 256 = 4 waves; wave computes 16 rows x FOUT. A-frag loaded directly
// from row-major fp32 X (8 contiguous floats), converted to hi/lo in regs.
// B-frags pre-swizzled in Wf (L2-resident). blockIdx.y selects L/R.
template <int FIN, int FOUT, bool BR>
__global__ __launch_bounds__(256, 4) void mfma_gemm_kernel(
    const float* __restrict__ X, const short* __restrict__ WfL,
    const short* __restrict__ WfR, const float* __restrict__ bL,
    const float* __restrict__ bR, float* __restrict__ YL,
    float* __restrict__ YR, int nrows) {
  constexpr int NC = FIN / 32, NT = FOUT / 16, TOT = NC * NT * 512;
  const short* Wf = blockIdx.y ? WfR : WfL;
  float* Y = blockIdx.y ? YR : YL;
  const int wave = threadIdx.x >> 6, lane = threadIdx.x & 63;
  const int quad = lane >> 4, ln16 = lane & 15;
  int rowA = blockIdx.x * 64 + wave * 16 + ln16;
  int rA = rowA < nrows ? rowA : nrows - 1;
  const float* xp = X + (size_t)rA * FIN + quad * 8;

  f32x4 acc[NT];
  #pragma unroll
  for (int t = 0; t < NT; t++) acc[t] = (f32x4){0.f, 0.f, 0.f, 0.f};

  #pragma unroll
  for (int c = 0; c < NC; c++) {
    float4 a0 = *(const float4*)(xp + c * 32);
    float4 a1 = *(const float4*)(xp + c * 32 + 4);
    float av[8] = {a0.x, a0.y, a0.z, a0.w, a1.x, a1.y, a1.z, a1.w};
    short8 ah, al;
    #pragma unroll
    for (int j = 0; j < 8; j++) {
      short h, l;
      cvt_hilo(av[j], h, l);
      ah[j] = h;
      al[j] = l;
    }
    const short* wp = Wf + c * NT * 512 + lane * 8;
    #pragma unroll
    for (int t = 0; t < NT; t++) {
      short8 bh = *(const short8*)(wp + t * 512);
      short8 bl = *(const short8*)(wp + t * 512 + TOT);
      acc[t] = __builtin_amdgcn_mfma_f32_16x16x32_bf16(ah, bh, acc[t], 0, 0, 0);
      acc[t] = __builtin_amdgcn_mfma_f32_16x16x32_bf16(al, bh, acc[t], 0, 0, 0);
      acc[t] = __builtin_amdgcn_mfma_f32_16x16x32_bf16(ah, bl, acc[t], 0, 0, 0);
    }
  }

  const float* bias = blockIdx.y ? bR : bL;
  const int rbase = blockIdx.x * 64 + wave * 16 + quad * 4;
  #pragma unroll
  for (int t = 0; t < NT; t++) {
    float bv = 0.f;
    if constexpr (BR) bv = bias[t * 16 + ln16];
    #pragma unroll
    for (int r = 0; r < 4; r++) {
      int rr = rbase + r;
      if (rr >= nrows) continue;
      float v = acc[t][r];
      if constexpr (BR) v = fmaxf(v + bv, 0.f);
      Y[(size_t)rr * FOUT + t * 16 + ln16] = v;
    }
  }
}

// ---------- fused GAT layer -------------------------------------------------
template <int H>
__global__ __launch_bounds__(256) void gat_fused_kernel(
    const float* __restrict__ xl, const float* __restrict__ xr,
    const int* __restrict__ csr_src, const int* __restrict__ row_end,
    const int* __restrict__ deg, const float* __restrict__ att,
    const float* __restrict__ res, const float* __restrict__ g,
    const float* __restrict__ b, float* __restrict__ y, int n,
    float resScale, int doRelu) {
  int row = blockIdx.x * 4 + (threadIdx.x >> 6);
  if (row >= n) return;
  int l = threadIdx.x & 63;
  int half = l >> 5;
  int ll = l & 31;
  int c = ll * 4;
  int end = row_end[row];
  int dg = deg[row];
  int start = end - dg;
  int cnt = (dg + 1 - half) >> 1;

  const int rofs = row * 512 + ll * 16;
  const f4v xrv = __builtin_nontemporal_load((const f4v*)((const char*)xr + rofs));
  const f4v av = *(const f4v*)&att[c];

  float s = 0.f;
  float a0 = 0.f, a1 = 0.f, a2 = 0.f, a3 = 0.f;

  int idx = start + half;
  f4v xn = {0.f, 0.f, 0.f, 0.f};
  if (cnt > 0) {
    int s0 = csr_src[idx];
    xn = *(const f4v*)((const char*)xl + s0 * 512 + ll * 16);
  }
  for (int i = 0; i < cnt; i++) {
    f4v xv = xn;
    if (i + 1 < cnt) {
      int sn = csr_src[idx + 2];
      xn = *(const f4v*)((const char*)xl + sn * 512 + ll * 16);
    }
    idx += 2;
    float v0 = xv.x + xrv.x; v0 = v0 > 0.f ? v0 : NEG_SLOPE * v0;
    float v1 = xv.y + xrv.y; v1 = v1 > 0.f ? v1 : NEG_SLOPE * v1;
    float v2 = xv.z + xrv.z; v2 = v2 > 0.f ? v2 : NEG_SLOPE * v2;
    float v3 = xv.w + xrv.w; v3 = v3 > 0.f ? v3 : NEG_SLOPE * v3;
    float p = v0 * av.x + v1 * av.y + v2 * av.z + v3 * av.w;
    if constexpr (H == 1) {
      #pragma unroll
      for (int o = 16; o; o >>= 1) p += __shfl_xor(p, o);
    } else {
      #pragma unroll
      for (int o = 4; o; o >>= 1) p += __shfl_xor(p, o);
    }
    float e = __expf(p);
    s += e;
    a0 += e * xv.x; a1 += e * xv.y; a2 += e * xv.z; a3 += e * xv.w;
  }
  s  += __shfl_xor(s, 32);
  a0 += __shfl_xor(a0, 32);
  a1 += __shfl_xor(a1, 32);
  a2 += __shfl_xor(a2, 32);
  a3 += __shfl_xor(a3, 32);

  float inv = 1.f / s;
  float o0 = a0 * inv, o1 = a1 * inv, o2 = a2 * inv, o3 = a3 * inv;

  float sum = o0 + o1 + o2 + o3;
  float sq = o0 * o0 + o1 * o1 + o2 * o2 + o3 * o3;
  #pragma unroll
  for (int o = 16; o; o >>= 1) { sum += __shfl_xor(sum, o); sq += __shfl_xor(sq, o); }
  float mean = sum * (1.f / 128.f);
  float var = sq * (1.f / 128.f) - mean * mean;
  float rstd = rsqrtf(var + 1e-5f);
  const f4v gv = *(const f4v*)&g[c];
  const f4v bv = *(const f4v*)&b[c];
  float r0 = (o0 - mean) * rstd * gv.x + bv.x;
  float r1 = (o1 - mean) * rstd * gv.y + bv.y;
  float r2 = (o2 - mean) * rstd * gv.z + bv.z;
  float r3 = (o3 - mean) * rstd * gv.w + bv.w;
  if (res) {
    const f4v rv = __builtin_nontemporal_load((const f4v*)((const char*)res + rofs));
    r0 += resScale * rv.x; r1 += resScale * rv.y;
    r2 += resScale * rv.z; r3 += resScale * rv.w;
  }
  if (doRelu) {
    r0 = fmaxf(r0, 0.f); r1 = fmaxf(r1, 0.f);
    r2 = fmaxf(r2, 0.f); r3 = fmaxf(r3, 0.f);
  }
  if (half == 0) {
    f4v o = {r0, r1, r2, r3};
    *(f4v*)((char*)y + rofs) = o;
  }
}

// ---------- final heads ----------
__global__ __launch_bounds__(256) void head_out_kernel(
    const float* __restrict__ t_rtt, const float* __restrict__ t_ret,
    const float* __restrict__ w2r, const float* __restrict__ b2r,
    const float* __restrict__ w2e, const float* __restrict__ b2e,
    float* __restrict__ out, int n) {
  int row = blockIdx.x * 4 + (threadIdx.x >> 6);
  int l = threadIdx.x & 63;
  if (row >= n) return;
  float a = t_rtt[(size_t)row * 64 + l] * w2r[l];
  float c = t_ret[(size_t)row * 64 + l] * w2e[l];
  #pragma unroll
  for (int o = 32; o; o >>= 1) { a += __shfl_xor(a, o); c += __shfl_xor(c, o); }
  if (l == 0) {
    out[(size_t)row * 2 + 0] = a + b2r[0];
    out[(size_t)row * 2 + 1] = c + b2e[0];
  }
}

// ---------- launch ----------
extern "C" void kernel_launch(void* const* d_in, const int* in_sizes, int n_in,
                              void* d_out, int out_size, void* d_ws,
                              size_t ws_size, hipStream_t stream) {
  const float* x       = (const float*)d_in[0];
  const int*   ei      = (const int*)d_in[1];
  const float* ln_in_g = (const float*)d_in[2];
  const float* ln_in_b = (const float*)d_in[3];
  const float* w_l1    = (const float*)d_in[4];
  const float* w_r1    = (const float*)d_in[5];
  const float* att1    = (const float*)d_in[6];
  const float* ln1_g   = (const float*)d_in[7];
  const float* ln1_b   = (const float*)d_in[8];
  const float* w_l2    = (const float*)d_in[9];
  const float* w_r2    = (const float*)d_in[10];
  const float* att2    = (const float*)d_in[11];
  const float* ln2_g   = (const float*)d_in[12];
  const float* ln2_b   = (const float*)d_in[13];
  const float* w_l3    = (const float*)d_in[14];
  const float* w_r3    = (const float*)d_in[15];
  const float* att3    = (const float*)d_in[16];
  const float* ln3_g   = (const float*)d_in[17];
  const float* ln3_b   = (const float*)d_in[18];
  const float* rtt_w1  = (const float*)d_in[19];
  const float* rtt_b1  = (const float*)d_in[20];
  const float* rtt_w2  = (const float*)d_in[21];
  const float* rtt_b2  = (const float*)d_in[22];
  const float* ret_w1  = (const float*)d_in[23];
  const float* ret_b1  = (const float*)d_in[24];
  const float* ret_w2  = (const float*)d_in[25];
  const float* ret_b2  = (const float*)d_in[26];

  const int N = in_sizes[0] / 64;
  const int E = in_sizes[1] / 2;
  const int ET = E + N;
  const size_t NF = (size_t)N * 128;

  float* A = (float*)d_ws;            // node features h / residual
  float* B = A + NF;                  // xl (later rtt hidden)
  float* C = B + NF;                  // xr (later ret hidden)
  int* deg     = (int*)(C + NF);      // N
  int* rowcur  = deg + N;             // N (row_end after scatter)
  int* incl    = rowcur + N;          // N
  int* bsums   = incl + N;            // 1024
  int* csr_src = bsums + 1024;        // ET
  // W fragment buffers (bf16 hi/lo), 64B-aligned
  short* wf = (short*)(((uintptr_t)(csr_src + ET) + 63) & ~(uintptr_t)63);

  float* out = (float*)d_out;

  // segments: wl1, wr1, wl2, wr2, wl3, wr3, rtt_w1, ret_w1
  const int segsz[8] = {64 * 128, 64 * 128, 128 * 128, 128 * 128,
                        128 * 128, 128 * 128, 128 * 64, 128 * 64};
  PrepArgs pa;
  pa.w[0] = w_l1; pa.w[1] = w_r1; pa.w[2] = w_l2; pa.w[3] = w_r2;
  pa.w[4] = w_l3; pa.w[5] = w_r3; pa.w[6] = rtt_w1; pa.w[7] = ret_w1;
  pa.fout[0] = 128; pa.fout[1] = 128; pa.fout[2] = 128; pa.fout[3] = 128;
  pa.fout[4] = 128; pa.fout[5] = 128; pa.fout[6] = 64; pa.fout[7] = 64;
  int acc = 0;
  short* op = wf;
  for (int s = 0; s < 8; s++) {
    pa.cum[s] = acc;
    pa.o[s] = op;
    op += 2 * segsz[s];  // hi + lo
    acc += segsz[s];
  }
  pa.cum[8] = acc;

  const int rowBlocks  = (N + 3) / 4;
  const int mmBlocks   = (N + 63) / 64;
  const int NB = (N + 1023) / 1024;
  dim3 mmGrid(mmBlocks, 2);

  // ---- W fragment prep ----
  prep_w_kernel<<<(acc + 255) / 256, 256, 0, stream>>>(pa);

  // ---- CSR build (by dst) ----
  fill_ones_kernel<<<(N + 255) / 256, 256, 0, stream>>>(deg, N);
  degree_count_kernel<<<(E + 255) / 256, 256, 0, stream>>>(ei, E, deg);
  scan1_kernel<<<NB, 1024, 0, stream>>>(deg, N, incl, bsums);
  scan2_kernel<<<1, 1024, 0, stream>>>(bsums, NB);
  scan3_kernel<<<NB, 1024, 0, stream>>>(incl, deg, bsums, N, rowcur);
  scatter_kernel<<<(ET + 255) / 256, 256, 0, stream>>>(ei, E, ET, rowcur, csr_src);

  // ---- input layernorm ----
  ln64_kernel<<<rowBlocks, 256, 0, stream>>>(x, ln_in_g, ln_in_b, A, N);

  // ---- layer 0: 64 -> 128, 4 heads, no residual, relu ----
  mfma_gemm_kernel<64, 128, false><<<mmGrid, 256, 0, stream>>>(
      A, pa.o[0], pa.o[1], nullptr, nullptr, B, C, N);
  gat_fused_kernel<4><<<rowBlocks, 256, 0, stream>>>(
      B, C, csr_src, rowcur, deg, att1, nullptr, ln1_g, ln1_b, A, N, 0.f, 1);

  // ---- layer 1: 128 -> 128, 4 heads, residual 0.1, relu ----
  mfma_gemm_kernel<128, 128, false><<<mmGrid, 256, 0, stream>>>(
      A, pa.o[2], pa.o[3], nullptr, nullptr, B, C, N);
  gat_fused_kernel<4><<<rowBlocks, 256, 0, stream>>>(
      B, C, csr_src, rowcur, deg, att2, A, ln2_g, ln2_b, A, N, 0.1f, 1);

  // ---- layer 2: 128 -> 128, 1 head, residual 0.1, no relu ----
  mfma_gemm_kernel<128, 128, false><<<mmGrid, 256, 0, stream>>>(
      A, pa.o[4], pa.o[5], nullptr, nullptr, B, C, N);
  gat_fused_kernel<1><<<rowBlocks, 256, 0, stream>>>(
      B, C, csr_src, rowcur, deg, att3, A, ln3_g, ln3_b, A, N, 0.1f, 0);

  // ---- prediction heads (rtt/ret split across blockIdx.y) ----
  mfma_gemm_kernel<128, 64, true><<<mmGrid, 256, 0, stream>>>(
      A, pa.o[6], pa.o[7], rtt_b1, ret_b1, B, C, N);
  head_out_kernel<<<rowBlocks, 256, 0, stream>>>(B, C, rtt_w2, rtt_b2, ret_w2,
                                                 ret_b2, out, N);
}

// Round 8
// 691.747 us; speedup vs baseline: 3.8718x; 1.0026x over previous
//
#include <hip/hip_runtime.h>
#include <hip/hip_bf16.h>
#include <cstdint>
#include <cstddef>

#define NEG_SLOPE 0.2f

typedef float f4v __attribute__((ext_vector_type(4)));
typedef short short8 __attribute__((ext_vector_type(8)));
typedef float f32x4 __attribute__((ext_vector_type(4)));

// fp32 -> 3x bf16 (h,m exact chops; l = RN of remainder). h+m+l = v to
// ~2^-24 rel. GEMM keeps products {hh,hm,mh,hl,mm,lh} -> fp32-grade result.
__device__ __forceinline__ void cvt3(float v, short& h, short& m, short& l) {
  unsigned u = __builtin_bit_cast(unsigned, v);
  h = (short)(u >> 16);
  float hf = __builtin_bit_cast(float, u & 0xFFFF0000u);
  float r1 = v - hf;
  unsigned u1 = __builtin_bit_cast(unsigned, r1);
  m = (short)(u1 >> 16);
  float mf = __builtin_bit_cast(float, u1 & 0xFFFF0000u);
  l = __builtin_bit_cast(short, __float2bfloat16(r1 - mf));
}

// ---------- CSR build ----------

__global__ __launch_bounds__(256) void fill_ones_kernel(int* __restrict__ p, int n) {
  int i = blockIdx.x * 256 + threadIdx.x;
  if (i < n) p[i] = 1;  // self-loop contributes degree 1
}

__global__ __launch_bounds__(256) void degree_count_kernel(
    const int* __restrict__ ei, int E, int* __restrict__ deg) {
  int e = blockIdx.x * 256 + threadIdx.x;
  if (e < E) atomicAdd(&deg[ei[E + e]], 1);
}

__global__ __launch_bounds__(1024) void scan1_kernel(
    const int* __restrict__ deg, int n, int* __restrict__ incl,
    int* __restrict__ blocksums) {
  __shared__ int sm[1024];
  int t = threadIdx.x;
  int i = blockIdx.x * 1024 + t;
  sm[t] = (i < n) ? deg[i] : 0;
  __syncthreads();
  #pragma unroll
  for (int o = 1; o < 1024; o <<= 1) {
    int a = (t >= o) ? sm[t - o] : 0;
    __syncthreads();
    sm[t] += a;
    __syncthreads();
  }
  if (i < n) incl[i] = sm[t];
  if (t == 1023) blocksums[blockIdx.x] = sm[t];
}

__global__ __launch_bounds__(1024) void scan2_kernel(int* __restrict__ bs, int nb) {
  __shared__ int sm[1024];
  int t = threadIdx.x;
  sm[t] = (t < nb) ? bs[t] : 0;
  __syncthreads();
  #pragma unroll
  for (int o = 1; o < 1024; o <<= 1) {
    int a = (t >= o) ? sm[t - o] : 0;
    __syncthreads();
    sm[t] += a;
    __syncthreads();
  }
  if (t < nb) bs[t] = sm[t];
}

__global__ __launch_bounds__(1024) void scan3_kernel(
    const int* __restrict__ incl, const int* __restrict__ deg,
    const int* __restrict__ bs, int n, int* __restrict__ rowcur) {
  int i = blockIdx.x * 1024 + threadIdx.x;
  if (i >= n) return;
  int off = (blockIdx.x > 0) ? bs[blockIdx.x - 1] : 0;
  rowcur[i] = incl[i] - deg[i] + off;
}

__global__ __launch_bounds__(256) void scatter_kernel(
    const int* __restrict__ ei, int E, int ET, int* __restrict__ rowcur,
    int* __restrict__ csr_src) {
  int e = blockIdx.x * 256 + threadIdx.x;
  if (e >= ET) return;
  int s, d;
  if (e < E) { s = ei[e]; d = ei[E + e]; }
  else       { s = e - E; d = s; }
  int pos = atomicAdd(&rowcur[d], 1);
  csr_src[pos] = s;
}

// ---------- W -> MFMA B-fragment layout (triple bf16 planes) ----------
struct PrepArgs {
  const float* w[8];
  short* o[8];
  int fout[8];
  int cum[9];
};

__global__ __launch_bounds__(256) void prep_w_kernel(PrepArgs pa) {
  int i = blockIdx.x * 256 + threadIdx.x;
  if (i >= pa.cum[8]) return;
  int s = 0;
  while (i >= pa.cum[s + 1]) s++;
  int li = i - pa.cum[s];
  int FOUT = pa.fout[s];
  int NT = FOUT >> 4;
  int sz = pa.cum[s + 1] - pa.cum[s];
  int c = li / (NT * 512);
  int r1 = li % (NT * 512);
  int t = r1 >> 9;
  int e = r1 & 511;
  int lane = e >> 3, j = e & 7;
  int k = c * 32 + (lane >> 4) * 8 + j;
  int n = t * 16 + (lane & 15);
  float v = pa.w[s][k * FOUT + n];
  short h, m, l;
  cvt3(v, h, m, l);
  pa.o[s][li] = h;
  pa.o[s][li + sz] = m;
  pa.o[s][li + 2 * sz] = l;
}

// 6-term triple-split MFMA accumulate for one tile
#define MFMA6(ah, am, al, bh, bm, bl, acc)                                   \
  acc = __builtin_amdgcn_mfma_f32_16x16x32_bf16(ah, bh, acc, 0, 0, 0);      \
  acc = __builtin_amdgcn_mfma_f32_16x16x32_bf16(ah, bm, acc, 0, 0, 0);      \
  acc = __builtin_amdgcn_mfma_f32_16x16x32_bf16(am, bh, acc, 0, 0, 0);      \
  acc = __builtin_amdgcn_mfma_f32_16x16x32_bf16(ah, bl, acc, 0, 0, 0);      \
  acc = __builtin_amdgcn_mfma_f32_16x16x32_bf16(am, bm, acc, 0, 0, 0);      \
  acc = __builtin_amdgcn_mfma_f32_16x16x32_bf16(al, bh, acc, 0, 0, 0);

// ---------- layer-0 GEMM with fused input LayerNorm(64) --------------------
// FIN=64, FOUT=128. Row rA spread over 4 quads (16 elems each); 2 shuffle
// rounds (xor 16,32) give row mean/var; normalize before triple-split.
__global__ __launch_bounds__(256, 4) void mfma_gemm_ln_kernel(
    const float* __restrict__ X, const float* __restrict__ lng,
    const float* __restrict__ lnb, const short* __restrict__ WfL,
    const short* __restrict__ WfR, float* __restrict__ YL,
    float* __restrict__ YR, int nrows) {
  constexpr int NT = 8, TOT = 2 * NT * 512;
  const short* Wf = blockIdx.y ? WfR : WfL;
  float* Y = blockIdx.y ? YR : YL;
  const int wave = threadIdx.x >> 6, lane = threadIdx.x & 63;
  const int quad = lane >> 4, ln16 = lane & 15;
  int rowA = blockIdx.x * 64 + wave * 16 + ln16;
  int rA = rowA < nrows ? rowA : nrows - 1;
  const float* xp = X + (size_t)rA * 64 + quad * 8;

  float av[16];
  *(float4*)&av[0]  = *(const float4*)(xp);
  *(float4*)&av[4]  = *(const float4*)(xp + 4);
  *(float4*)&av[8]  = *(const float4*)(xp + 32);
  *(float4*)&av[12] = *(const float4*)(xp + 36);

  float s = 0.f, sq = 0.f;
  #pragma unroll
  for (int j = 0; j < 16; j++) { s += av[j]; sq += av[j] * av[j]; }
  s  += __shfl_xor(s, 16);  s  += __shfl_xor(s, 32);
  sq += __shfl_xor(sq, 16); sq += __shfl_xor(sq, 32);
  float mean = s * (1.f / 64.f);
  float var = sq * (1.f / 64.f) - mean * mean;
  float rstd = rsqrtf(var + 1e-5f);

  f32x4 acc[NT];
  #pragma unroll
  for (int t = 0; t < NT; t++) acc[t] = (f32x4){0.f, 0.f, 0.f, 0.f};

  #pragma unroll
  for (int c = 0; c < 2; c++) {
    float4 gv0 = *(const float4*)&lng[quad * 8 + c * 32];
    float4 gv1 = *(const float4*)&lng[quad * 8 + c * 32 + 4];
    float4 bv0 = *(const float4*)&lnb[quad * 8 + c * 32];
    float4 bv1 = *(const float4*)&lnb[quad * 8 + c * 32 + 4];
    float gg[8] = {gv0.x, gv0.y, gv0.z, gv0.w, gv1.x, gv1.y, gv1.z, gv1.w};
    float bb[8] = {bv0.x, bv0.y, bv0.z, bv0.w, bv1.x, bv1.y, bv1.z, bv1.w};
    short8 ah, am, al;
    #pragma unroll
    for (int j = 0; j < 8; j++) {
      float v = (av[c * 8 + j] - mean) * rstd * gg[j] + bb[j];
      short h, m, l;
      cvt3(v, h, m, l);
      ah[j] = h; am[j] = m; al[j] = l;
    }
    const short* wp = Wf + c * NT * 512 + lane * 8;
    #pragma unroll
    for (int t = 0; t < NT; t++) {
      short8 bh = *(const short8*)(wp + t * 512);
      short8 bm = *(const short8*)(wp + t * 512 + TOT);
      short8 bl = *(const short8*)(wp + t * 512 + 2 * TOT);
      MFMA6(ah, am, al, bh, bm, bl, acc[t]);
    }
  }

  const int rbase = blockIdx.x * 64 + wave * 16 + quad * 4;
  #pragma unroll
  for (int t = 0; t < NT; t++)
    #pragma unroll
    for (int r = 0; r < 4; r++) {
      int rr = rbase + r;
      if (rr < nrows) Y[(size_t)rr * 128 + t * 16 + ln16] = acc[t][r];
    }
}

// ---------- generic MFMA GEMM: FIN=128 -> FOUT=128 (no LDS/barriers) -------
__global__ __launch_bounds__(256, 4) void mfma_gemm_kernel(
    const float* __restrict__ X, const short* __restrict__ WfL,
    const short* __restrict__ WfR, float* __restrict__ YL,
    float* __restrict__ YR, int nrows) {
  constexpr int NC = 4, NT = 8, TOT = NC * NT * 512;
  const short* Wf = blockIdx.y ? WfR : WfL;
  float* Y = blockIdx.y ? YR : YL;
  const int wave = threadIdx.x >> 6, lane = threadIdx.x & 63;
  const int quad = lane >> 4, ln16 = lane & 15;
  int rowA = blockIdx.x * 64 + wave * 16 + ln16;
  int rA = rowA < nrows ? rowA : nrows - 1;
  const float* xp = X + (size_t)rA * 128 + quad * 8;

  f32x4 acc[NT];
  #pragma unroll
  for (int t = 0; t < NT; t++) acc[t] = (f32x4){0.f, 0.f, 0.f, 0.f};

  #pragma unroll
  for (int c = 0; c < NC; c++) {
    float4 a0 = *(const float4*)(xp + c * 32);
    float4 a1 = *(const float4*)(xp + c * 32 + 4);
    float av[8] = {a0.x, a0.y, a0.z, a0.w, a1.x, a1.y, a1.z, a1.w};
    short8 ah, am, al;
    #pragma unroll
    for (int j = 0; j < 8; j++) {
      short h, m, l;
      cvt3(av[j], h, m, l);
      ah[j] = h; am[j] = m; al[j] = l;
    }
    const short* wp = Wf + c * NT * 512 + lane * 8;
    #pragma unroll
    for (int t = 0; t < NT; t++) {
      short8 bh = *(const short8*)(wp + t * 512);
      short8 bm = *(const short8*)(wp + t * 512 + TOT);
      short8 bl = *(const short8*)(wp + t * 512 + 2 * TOT);
      MFMA6(ah, am, al, bh, bm, bl, acc[t]);
    }
  }

  const int rbase = blockIdx.x * 64 + wave * 16 + quad * 4;
  #pragma unroll
  for (int t = 0; t < NT; t++)
    #pragma unroll
    for (int r = 0; r < 4; r++) {
      int rr = rbase + r;
      if (rr < nrows) Y[(size_t)rr * 128 + t * 16 + ln16] = acc[t][r];
    }
}

// ---------- head GEMM fused with final dot: out[row,sel] -------------------
// Y = relu(X@W1 + b1) [N,64]; out[row*2+sel] = Y.w2 + b2. blockIdx.y = sel.
__global__ __launch_bounds__(256, 4) void mfma_head_kernel(
    const float* __restrict__ X, const short* __restrict__ Wf1,
    const float* __restrict__ b1a, const float* __restrict__ w2a,
    const float* __restrict__ b2a, const short* __restrict__ Wf2,
    const float* __restrict__ b1b, const float* __restrict__ w2b,
    const float* __restrict__ b2b, float* __restrict__ out, int nrows) {
  constexpr int NC = 4, NT = 4, TOT = NC * NT * 512;
  const int sel = blockIdx.y;
  const short* Wf = sel ? Wf2 : Wf1;
  const float* b1 = sel ? b1b : b1a;
  const float* w2 = sel ? w2b : w2a;
  const float bb2 = sel ? b2b[0] : b2a[0];
  const int wave = threadIdx.x >> 6, lane = threadIdx.x & 63;
  const int quad = lane >> 4, ln16 = lane & 15;
  int rowA = blockIdx.x * 64 + wave * 16 + ln16;
  int rA = rowA < nrows ? rowA : nrows - 1;
  const float* xp = X + (size_t)rA * 128 + quad * 8;

  f32x4 acc[NT];
  #pragma unroll
  for (int t = 0; t < NT; t++) acc[t] = (f32x4){0.f, 0.f, 0.f, 0.f};

  #pragma unroll
  for (int c = 0; c < NC; c++) {
    float4 a0 = *(const float4*)(xp + c * 32);
    float4 a1 = *(const float4*)(xp + c * 32 + 4);
    float av[8] = {a0.x, a0.y, a0.z, a0.w, a1.x, a1.y, a1.z, a1.w};
    short8 ah, am, al;
    #pragma unroll
    for (int j = 0; j < 8; j++) {
      short h, m, l;
      cvt3(av[j], h, m, l);
      ah[j] = h; am[j] = m; al[j] = l;
    }
    const short* wp = Wf + c * NT * 512 + lane * 8;
    #pragma unroll
    for (int t = 0; t < NT; t++) {
      short8 bh = *(const short8*)(wp + t * 512);
      short8 bm = *(const short8*)(wp + t * 512 + TOT);
      short8 bl = *(const short8*)(wp + t * 512 + 2 * TOT);
      MFMA6(ah, am, al, bh, bm, bl, acc[t]);
    }
  }

  float pr[4] = {0.f, 0.f, 0.f, 0.f};
  #pragma unroll
  for (int t = 0; t < NT; t++) {
    float bv = b1[t * 16 + ln16];
    float wv = w2[t * 16 + ln16];
    #pragma unroll
    for (int r = 0; r < 4; r++)
      pr[r] += fmaxf(acc[t][r] + bv, 0.f) * wv;
  }
  #pragma unroll
  for (int o = 1; o < 16; o <<= 1)
    #pragma unroll
    for (int r = 0; r < 4; r++) pr[r] += __shfl_xor(pr[r], o);
  if (ln16 == 0) {
    const int rbase = blockIdx.x * 64 + wave * 16 + quad * 4;
    #pragma unroll
    for (int r = 0; r < 4; r++) {
      int rr = rbase + r;
      if (rr < nrows) out[(size_t)rr * 2 + sel] = pr[r] + bb2;
    }
  }
}

// ---------- fused GAT layer -------------------------------------------------
// Wave per dst row; each 16-lane QUARTER processes its own edge stream
// (lane owns 8 channels = 2xfloat4) -> 8 loads in flight/wave. Plain softmax
// sums; quarters combine via xor-16/32 adds. Fused LN + residual + relu.
template <int H>
__global__ __launch_bounds__(256) void gat_fused_kernel(
    const float* __restrict__ xl, const float* __restrict__ xr,
    const int* __restrict__ csr_src, const int* __restrict__ row_end,
    const int* __restrict__ deg, const float* __restrict__ att,
    const float* __restrict__ res, const float* __restrict__ g,
    const float* __restrict__ b, float* __restrict__ y, int n,
    float resScale, int doRelu) {
  int row = blockIdx.x * 4 + (threadIdx.x >> 6);
  if (row >= n) return;
  int l = threadIdx.x & 63;
  int q = l >> 4;
  int ln = l & 15;
  int cb = ln * 32;  // byte offset of lane's 8-channel chunk
  int end = row_end[row];
  int dg = deg[row];
  int start = end - dg;
  int cnt = (dg - q + 3) >> 2;  // edges for this quarter (dg >= 1 always)

  const char* xrb = (const char*)xr + (size_t)row * 512 + cb;
  f4v xr0 = __builtin_nontemporal_load((const f4v*)xrb);
  f4v xr1 = __builtin_nontemporal_load((const f4v*)(xrb + 16));
  f4v av0 = *(const f4v*)((const char*)att + cb);
  f4v av1 = *(const f4v*)((const char*)att + cb + 16);

  float s = 0.f;
  float ac[8] = {0.f, 0.f, 0.f, 0.f, 0.f, 0.f, 0.f, 0.f};

  int idx = start + q;
  f4v xn0 = {0.f, 0.f, 0.f, 0.f}, xn1 = {0.f, 0.f, 0.f, 0.f};
  if (cnt > 0) {
    const char* p = (const char*)xl + (size_t)csr_src[idx] * 512 + cb;
    xn0 = *(const f4v*)p;
    xn1 = *(const f4v*)(p + 16);
  }
  for (int i = 0; i < cnt; i++) {
    f4v x0 = xn0, x1 = xn1;
    if (i + 1 < cnt) {
      const char* p = (const char*)xl + (size_t)csr_src[idx + 4] * 512 + cb;
      xn0 = *(const f4v*)p;
      xn1 = *(const f4v*)(p + 16);
    }
    idx += 4;
    float p0;
    {
      float v0 = x0.x + xr0.x; v0 = v0 > 0.f ? v0 : NEG_SLOPE * v0;
      float v1 = x0.y + xr0.y; v1 = v1 > 0.f ? v1 : NEG_SLOPE * v1;
      float v2 = x0.z + xr0.z; v2 = v2 > 0.f ? v2 : NEG_SLOPE * v2;
      float v3 = x0.w + xr0.w; v3 = v3 > 0.f ? v3 : NEG_SLOPE * v3;
      float v4 = x1.x + xr1.x; v4 = v4 > 0.f ? v4 : NEG_SLOPE * v4;
      float v5 = x1.y + xr1.y; v5 = v5 > 0.f ? v5 : NEG_SLOPE * v5;
      float v6 = x1.z + xr1.z; v6 = v6 > 0.f ? v6 : NEG_SLOPE * v6;
      float v7 = x1.w + xr1.w; v7 = v7 > 0.f ? v7 : NEG_SLOPE * v7;
      p0 = v0 * av0.x + v1 * av0.y + v2 * av0.z + v3 * av0.w +
           v4 * av1.x + v5 * av1.y + v6 * av1.z + v7 * av1.w;
    }
    if constexpr (H == 1) {  // logit over 128 ch = 16 lanes
      #pragma unroll
      for (int o = 1; o < 16; o <<= 1) p0 += __shfl_xor(p0, o);
    } else {                 // H=4: head = 32 ch = 4 lanes
      p0 += __shfl_xor(p0, 1);
      p0 += __shfl_xor(p0, 2);
    }
    float e = __expf(p0);
    s += e;
    ac[0] += e * x0.x; ac[1] += e * x0.y; ac[2] += e * x0.z; ac[3] += e * x0.w;
    ac[4] += e * x1.x; ac[5] += e * x1.y; ac[6] += e * x1.z; ac[7] += e * x1.w;
  }
  // combine the four quarter streams (plain sums)
  s += __shfl_xor(s, 16);
  s += __shfl_xor(s, 32);
  #pragma unroll
  for (int j = 0; j < 8; j++) {
    ac[j] += __shfl_xor(ac[j], 16);
    ac[j] += __shfl_xor(ac[j], 32);
  }

  float inv = 1.f / s;
  float ov[8];
  #pragma unroll
  for (int j = 0; j < 8; j++) ov[j] = ac[j] * inv;

  // LayerNorm over 128 (16 lanes of a quarter cover all channels)
  float sum = 0.f, sq = 0.f;
  #pragma unroll
  for (int j = 0; j < 8; j++) { sum += ov[j]; sq += ov[j] * ov[j]; }
  #pragma unroll
  for (int o = 1; o < 16; o <<= 1) {
    sum += __shfl_xor(sum, o);
    sq += __shfl_xor(sq, o);
  }
  float mean = sum * (1.f / 128.f);
  float var = sq * (1.f / 128.f) - mean * mean;
  float rstd = rsqrtf(var + 1e-5f);

  f4v gv0 = *(const f4v*)((const char*)g + cb);
  f4v gv1 = *(const f4v*)((const char*)g + cb + 16);
  f4v bv0 = *(const f4v*)((const char*)b + cb);
  f4v bv1 = *(const f4v*)((const char*)b + cb + 16);
  float gg[8] = {gv0.x, gv0.y, gv0.z, gv0.w, gv1.x, gv1.y, gv1.z, gv1.w};
  float bb[8] = {bv0.x, bv0.y, bv0.z, bv0.w, bv1.x, bv1.y, bv1.z, bv1.w};
  float rv[8];
  #pragma unroll
  for (int j = 0; j < 8; j++) rv[j] = (ov[j] - mean) * rstd * gg[j] + bb[j];
  if (res) {
    const char* rb = (const char*)res + (size_t)row * 512 + cb;
    f4v r0 = __builtin_nontemporal_load((const f4v*)rb);
    f4v r1 = __builtin_nontemporal_load((const f4v*)(rb + 16));
    rv[0] += resScale * r0.x; rv[1] += resScale * r0.y;
    rv[2] += resScale * r0.z; rv[3] += resScale * r0.w;
    rv[4] += resScale * r1.x; rv[5] += resScale * r1.y;
    rv[6] += resScale * r1.z; rv[7] += resScale * r1.w;
  }
  if (doRelu) {
    #pragma unroll
    for (int j = 0; j < 8; j++) rv[j] = fmaxf(rv[j], 0.f);
  }
  if (q == 0) {
    char* yb = (char*)y + (size_t)row * 512 + cb;
    *(f4v*)yb = (f4v){rv[0], rv[1], rv[2], rv[3]};
    *(f4v*)(yb + 16) = (f4v){rv[4], rv[5], rv[6], rv[7]};
  }
}

// ---------- launch ----------
extern "C" void kernel_launch(void* const* d_in, const int* in_sizes, int n_in,
                              void* d_out, int out_size, void* d_ws,
                              size_t ws_size, hipStream_t stream) {
  const float* x       = (const float*)d_in[0];
  const int*   ei      = (const int*)d_in[1];
  const float* ln_in_g = (const float*)d_in[2];
  const float* ln_in_b = (const float*)d_in[3];
  const float* w_l1    = (const float*)d_in[4];
  const float* w_r1    = (const float*)d_in[5];
  const float* att1    = (const float*)d_in[6];
  const float* ln1_g   = (const float*)d_in[7];
  const float* ln1_b   = (const float*)d_in[8];
  const float* w_l2    = (const float*)d_in[9];
  const float* w_r2    = (const float*)d_in[10];
  const float* att2    = (const float*)d_in[11];
  const float* ln2_g   = (const float*)d_in[12];
  const float* ln2_b   = (const float*)d_in[13];
  const float* w_l3    = (const float*)d_in[14];
  const float* w_r3    = (const float*)d_in[15];
  const float* att3    = (const float*)d_in[16];
  const float* ln3_g   = (const float*)d_in[17];
  const float* ln3_b   = (const float*)d_in[18];
  const float* rtt_w1  = (const float*)d_in[19];
  const float* rtt_b1  = (const float*)d_in[20];
  const float* rtt_w2  = (const float*)d_in[21];
  const float* rtt_b2  = (const float*)d_in[22];
  const float* ret_w1  = (const float*)d_in[23];
  const float* ret_b1  = (const float*)d_in[24];
  const float* ret_w2  = (const float*)d_in[25];
  const float* ret_b2  = (const float*)d_in[26];

  const int N = in_sizes[0] / 64;
  const int E = in_sizes[1] / 2;
  const int ET = E + N;
  const size_t NF = (size_t)N * 128;

  float* A = (float*)d_ws;            // node features h / residual
  float* B = A + NF;                  // xl
  float* C = B + NF;                  // xr
  int* deg     = (int*)(C + NF);      // N
  int* rowcur  = deg + N;             // N (row_end after scatter)
  int* incl    = rowcur + N;          // N
  int* bsums   = incl + N;            // 1024
  int* csr_src = bsums + 1024;        // ET
  short* wf = (short*)(((uintptr_t)(csr_src + ET) + 63) & ~(uintptr_t)63);

  float* out = (float*)d_out;

  // segments: wl1, wr1, wl2, wr2, wl3, wr3, rtt_w1, ret_w1
  const int segsz[8] = {64 * 128, 64 * 128, 128 * 128, 128 * 128,
                        128 * 128, 128 * 128, 128 * 64, 128 * 64};
  PrepArgs pa;
  pa.w[0] = w_l1; pa.w[1] = w_r1; pa.w[2] = w_l2; pa.w[3] = w_r2;
  pa.w[4] = w_l3; pa.w[5] = w_r3; pa.w[6] = rtt_w1; pa.w[7] = ret_w1;
  pa.fout[0] = 128; pa.fout[1] = 128; pa.fout[2] = 128; pa.fout[3] = 128;
  pa.fout[4] = 128; pa.fout[5] = 128; pa.fout[6] = 64; pa.fout[7] = 64;
  int acc = 0;
  short* op = wf;
  for (int s = 0; s < 8; s++) {
    pa.cum[s] = acc;
    pa.o[s] = op;
    op += 3 * segsz[s];  // h + m + l planes
    acc += segsz[s];
  }
  pa.cum[8] = acc;

  const int rowBlocks  = (N + 3) / 4;
  const int mmBlocks   = (N + 63) / 64;
  const int NB = (N + 1023) / 1024;
  dim3 mmGrid(mmBlocks, 2);

  // ---- W fragment prep ----
  prep_w_kernel<<<(acc + 255) / 256, 256, 0, stream>>>(pa);

  // ---- CSR build (by dst) ----
  fill_ones_kernel<<<(N + 255) / 256, 256, 0, stream>>>(deg, N);
  degree_count_kernel<<<(E + 255) / 256, 256, 0, stream>>>(ei, E, deg);
  scan1_kernel<<<NB, 1024, 0, stream>>>(deg, N, incl, bsums);
  scan2_kernel<<<1, 1024, 0, stream>>>(bsums, NB);
  scan3_kernel<<<NB, 1024, 0, stream>>>(incl, deg, bsums, N, rowcur);
  scatter_kernel<<<(ET + 255) / 256, 256, 0, stream>>>(ei, E, ET, rowcur, csr_src);

  // ---- layer 0: fused LN64 + GEMM 64->128, 4 heads, no residual, relu ----
  mfma_gemm_ln_kernel<<<mmGrid, 256, 0, stream>>>(
      x, ln_in_g, ln_in_b, pa.o[0], pa.o[1], B, C, N);
  gat_fused_kernel<4><<<rowBlocks, 256, 0, stream>>>(
      B, C, csr_src, rowcur, deg, att1, nullptr, ln1_g, ln1_b, A, N, 0.f, 1);

  // ---- layer 1: 128 -> 128, 4 heads, residual 0.1, relu ----
  mfma_gemm_kernel<<<mmGrid, 256, 0, stream>>>(A, pa.o[2], pa.o[3], B, C, N);
  gat_fused_kernel<4><<<rowBlocks, 256, 0, stream>>>(
      B, C, csr_src, rowcur, deg, att2, A, ln2_g, ln2_b, A, N, 0.1f, 1);

  // ---- layer 2: 128 -> 128, 1 head, residual 0.1, no relu ----
  mfma_gemm_kernel<<<mmGrid, 256, 0, stream>>>(A, pa.o[4], pa.o[5], B, C, N);
  gat_fused_kernel<1><<<rowBlocks, 256, 0, stream>>>(
      B, C, csr_src, rowcur, deg, att3, A, ln3_g, ln3_b, A, N, 0.1f, 0);

  // ---- prediction heads: GEMM + relu + final dot fused ----
  mfma_head_kernel<<<mmGrid, 256, 0, stream>>>(
      A, pa.o[6], rtt_b1, rtt_w2, rtt_b2, pa.o[7], ret_b1, ret_w2, ret_b2,
      out, N);
}